// Round 16
// baseline (767.315 us; speedup 1.0000x reference)
//
#include <hip/hip_runtime.h>

#define NN 50000
#define EE 800000
#define GG 256
#define IND 32
#define HID 108
#define NL 4
#define MB 782            // ceil(50000/64) M-tiles
#define LDSK 136          // LDS B row stride in halves (272 B = 17*16, conflict-safe)

typedef __attribute__((ext_vector_type(8))) _Float16 f16x8;
typedef __attribute__((ext_vector_type(4))) float floatx4;

__global__ void k_zero(int* deg) {
    int i = blockIdx.x * 256 + threadIdx.x;
    if (i < NN) deg[i] = 0;
}

__global__ void k_hist(const int* dst, int* deg) {
    int e = blockIdx.x * 256 + threadIdx.x;
    if (e < EE) atomicAdd(&deg[dst[e]], 1);
}

// Work-efficient single-block scan: 1024 threads x 49-element serial chunks.
__global__ __launch_bounds__(1024)
void k_scan(const int* __restrict__ deg, int* __restrict__ rp) {
    __shared__ int wsum[16];
    __shared__ int wexc[16];
    const int C = (NN + 1023) / 1024;   // 49
    int tid = threadIdx.x, lane = tid & 63, wv = tid >> 6;
    int base = tid * C;
    int sum = 0;
    for (int j = 0; j < C; j++) {
        int i = base + j;
        if (i < NN) sum += deg[i];
    }
    int x = sum;
    #pragma unroll
    for (int off = 1; off < 64; off <<= 1) {
        int y = __shfl_up(x, off, 64);
        if (lane >= off) x += y;
    }
    if (lane == 63) wsum[wv] = x;
    __syncthreads();
    if (tid == 0) {
        int run = 0;
        for (int w = 0; w < 16; w++) { wexc[w] = run; run += wsum[w]; }
    }
    __syncthreads();
    int running = wexc[wv] + x - sum;   // exclusive prefix for this thread's chunk
    if (tid == 0) rp[0] = 0;
    for (int j = 0; j < C; j++) {
        int i = base + j;
        if (i < NN) { running += deg[i]; rp[i + 1] = running; }
    }
}

__global__ void k_scatter(const int* src, const int* dst, const int* rp,
                          int* deg, int* cs) {
    int e = blockIdx.x * 256 + threadIdx.x;
    if (e < EE) {
        int d = dst[e];
        int pos = atomicSub(&deg[d], 1) - 1;
        cs[rp[d] + pos] = src[e];
    }
}

// Pack weights: fp16, transposed Bt[n][k], K padded to 128.
__global__ void k_pack(const float* __restrict__ W_pool, const float* __restrict__ b_pool,
                       const float* __restrict__ W_app, const float* __restrict__ b_app,
                       _Float16* Bt1, _Float16* Bt2, float* bb1) {
    int r = blockIdx.x * 256 + threadIdx.x;
    if (r < NL * 256 * 128) {
        int l = r / (256 * 128); int t = r % (256 * 128); int n = t / 128, k = t % 128;
        float v = 0.f;
        if (k < HID) {
            if (n < HID)                        v = W_pool[((size_t)l * HID + k) * HID + n];
            else if (n >= 128 && n < 128 + HID) v = W_app[((size_t)l * 216 + k) * HID + (n - 128)];
        }
        Bt1[r] = (_Float16)v; return;
    } r -= NL * 256 * 128;
    if (r < NL * 128 * 128) {
        int l = r / (128 * 128); int t = r % (128 * 128); int n = t / 128, k = t % 128;
        float v = (n < HID && k < HID) ? W_app[((size_t)l * 216 + 108 + k) * HID + n] : 0.f;
        Bt2[r] = (_Float16)v; return;
    } r -= NL * 128 * 128;
    if (r < NL * 256) {
        int l = r / 256, n = r % 256;
        float v = 0.f;
        if (n < HID) v = b_pool[l * HID + n];
        else if (n >= 128 && n < 128 + HID) v = b_app[l * HID + (n - 128)];
        bb1[r] = v;
    }
}

// embed: h fp32 (stride 108) + h16 fp16 (stride 128, zero-padded cols)
__global__ void k_embed(const float* __restrict__ feat, const float* __restrict__ W,
                        const float* __restrict__ b,
                        float* __restrict__ h, _Float16* __restrict__ h16) {
    int i = blockIdx.x * 256 + threadIdx.x;
    if (i >= NN * 128) return;
    int n = i >> 7, c = i & 127;
    if (c < HID) {
        float acc = b[c];
        const float* fr = feat + (size_t)n * IND;
        for (int k = 0; k < IND; k++) acc += fr[k] * W[k * HID + c];
        h[(size_t)n * HID + c] = acc;
        h16[i] = (_Float16)acc;
    } else {
        h16[i] = (_Float16)0.f;
    }
}

// mm1: C[64,128] = A(h16)[64,128] @ Bt^T + bias. nt=0 -> hp16=relu fp16; nt=1 -> part fp32
__global__ __launch_bounds__(256)
void k_mm1(const _Float16* __restrict__ A, const _Float16* __restrict__ Bt,
           const float* __restrict__ bias,
           _Float16* __restrict__ hp16, float* __restrict__ part) {
    __shared__ _Float16 Bl[128 * LDSK];
    int tid = threadIdx.x;
    int nt = blockIdx.y;
    const _Float16* Bsrc = Bt + (size_t)nt * 128 * 128;
    for (int i = tid; i < 128 * 16; i += 256) {
        int rr = i >> 4, g = i & 15;
        *(uint4*)&Bl[rr * LDSK + g * 8] = *(const uint4*)(Bsrc + rr * 128 + g * 8);
    }
    __syncthreads();
    int lane = tid & 63, wid = tid >> 6, lm = lane & 15, lq = lane >> 4;
    int m0 = blockIdx.x * 64;
    floatx4 acc[4][2];
    #pragma unroll
    for (int mi = 0; mi < 4; mi++)
        #pragma unroll
        for (int ni = 0; ni < 2; ni++) { floatx4 z = {0.f,0.f,0.f,0.f}; acc[mi][ni] = z; }
    f16x8 zf = {(_Float16)0, (_Float16)0, (_Float16)0, (_Float16)0,
                (_Float16)0, (_Float16)0, (_Float16)0, (_Float16)0};
    #pragma unroll
    for (int ks = 0; ks < 4; ks++) {
        f16x8 a[4], b[2];
        #pragma unroll
        for (int mi = 0; mi < 4; mi++) {
            int row = m0 + mi * 16 + lm;
            a[mi] = (row < NN) ? *(const f16x8*)(A + (size_t)row * 128 + ks * 32 + lq * 8) : zf;
        }
        #pragma unroll
        for (int ni = 0; ni < 2; ni++)
            b[ni] = *(const f16x8*)&Bl[(wid * 32 + ni * 16 + lm) * LDSK + ks * 32 + lq * 8];
        #pragma unroll
        for (int mi = 0; mi < 4; mi++)
            #pragma unroll
            for (int ni = 0; ni < 2; ni++)
                acc[mi][ni] = __builtin_amdgcn_mfma_f32_16x16x32_f16(a[mi], b[ni], acc[mi][ni], 0, 0, 0);
    }
    #pragma unroll
    for (int mi = 0; mi < 4; mi++)
        #pragma unroll
        for (int ni = 0; ni < 2; ni++) {
            int col = wid * 32 + ni * 16 + lm;
            float bc = bias[nt * 128 + col];
            #pragma unroll
            for (int r = 0; r < 4; r++) {
                int row = m0 + mi * 16 + lq * 4 + r;
                if (row < NN) {
                    float v = acc[mi][ni][r] + bc;
                    if (nt == 0) hp16[(size_t)row * 128 + col] = (_Float16)fmaxf(v, 0.f);
                    else         part[(size_t)row * 128 + col] = v;
                }
            }
        }
}

// agg16[n][:] = fp16(mean over in-neighbors of hp16)
__global__ __launch_bounds__(128)
void k_agg(const _Float16* __restrict__ hp16, const int* __restrict__ rp,
           const int* __restrict__ cs, _Float16* __restrict__ agg16) {
    __shared__ float asl[8][128];
    int n = blockIdx.x, tid = threadIdx.x;
    int t = tid & 15, q = tid >> 4;
    int s0 = rp[n], s1 = rp[n + 1];
    float a[8];
    #pragma unroll
    for (int j = 0; j < 8; j++) a[j] = 0.f;
    int co = t * 8;
    for (int e = s0 + q; e < s1; e += 8) {
        f16x8 v = *(const f16x8*)(hp16 + (size_t)cs[e] * 128 + co);
        #pragma unroll
        for (int j = 0; j < 8; j++) a[j] += (float)v[j];
    }
    #pragma unroll
    for (int j = 0; j < 8; j++) asl[q][co + j] = a[j];
    __syncthreads();
    int col = tid;
    float s = 0.f;
    #pragma unroll
    for (int qq = 0; qq < 8; qq++) s += asl[qq][col];
    int dg = s1 - s0;
    float inv = 1.0f / (float)((dg > 1) ? dg : 1);
    agg16[(size_t)n * 128 + col] = (_Float16)(s * inv);
}

// mm2: bu = agg16 @ Bt2^T + part; l2norm -> relu -> h += ; write h fp32 + h16
__global__ __launch_bounds__(256)
void k_mm2(const _Float16* __restrict__ A, const _Float16* __restrict__ Bt,
           const float* __restrict__ part,
           float* __restrict__ h, _Float16* __restrict__ h16) {
    __shared__ _Float16 Bl[128 * LDSK];
    __shared__ float ssl[64 * 4];
    __shared__ float scl[64];
    int tid = threadIdx.x;
    for (int i = tid; i < 128 * 16; i += 256) {
        int rr = i >> 4, g = i & 15;
        *(uint4*)&Bl[rr * LDSK + g * 8] = *(const uint4*)(Bt + rr * 128 + g * 8);
    }
    __syncthreads();
    int lane = tid & 63, wid = tid >> 6, lm = lane & 15, lq = lane >> 4;
    int m0 = blockIdx.x * 64;
    floatx4 acc[4][2];
    #pragma unroll
    for (int mi = 0; mi < 4; mi++)
        #pragma unroll
        for (int ni = 0; ni < 2; ni++) { floatx4 z = {0.f,0.f,0.f,0.f}; acc[mi][ni] = z; }
    f16x8 zf = {(_Float16)0, (_Float16)0, (_Float16)0, (_Float16)0,
                (_Float16)0, (_Float16)0, (_Float16)0, (_Float16)0};
    #pragma unroll
    for (int ks = 0; ks < 4; ks++) {
        f16x8 a[4], b[2];
        #pragma unroll
        for (int mi = 0; mi < 4; mi++) {
            int row = m0 + mi * 16 + lm;
            a[mi] = (row < NN) ? *(const f16x8*)(A + (size_t)row * 128 + ks * 32 + lq * 8) : zf;
        }
        #pragma unroll
        for (int ni = 0; ni < 2; ni++)
            b[ni] = *(const f16x8*)&Bl[(wid * 32 + ni * 16 + lm) * LDSK + ks * 32 + lq * 8];
        #pragma unroll
        for (int mi = 0; mi < 4; mi++)
            #pragma unroll
            for (int ni = 0; ni < 2; ni++)
                acc[mi][ni] = __builtin_amdgcn_mfma_f32_16x16x32_f16(a[mi], b[ni], acc[mi][ni], 0, 0, 0);
    }
    #pragma unroll
    for (int mi = 0; mi < 4; mi++)
        #pragma unroll
        for (int ni = 0; ni < 2; ni++) {
            int col = wid * 32 + ni * 16 + lm;
            #pragma unroll
            for (int r = 0; r < 4; r++) {
                int row = m0 + mi * 16 + lq * 4 + r;
                acc[mi][ni][r] = (row < NN) ? acc[mi][ni][r] + part[(size_t)row * 128 + col] : 0.f;
            }
        }
    float ss[4][4];
    #pragma unroll
    for (int mi = 0; mi < 4; mi++)
        #pragma unroll
        for (int r = 0; r < 4; r++)
            ss[mi][r] = acc[mi][0][r] * acc[mi][0][r] + acc[mi][1][r] * acc[mi][1][r];
    #pragma unroll
    for (int off = 1; off < 16; off <<= 1)
        #pragma unroll
        for (int mi = 0; mi < 4; mi++)
            #pragma unroll
            for (int r = 0; r < 4; r++)
                ss[mi][r] += __shfl_xor(ss[mi][r], off, 64);
    if (lm == 0) {
        #pragma unroll
        for (int mi = 0; mi < 4; mi++)
            #pragma unroll
            for (int r = 0; r < 4; r++)
                ssl[(mi * 16 + lq * 4 + r) * 4 + wid] = ss[mi][r];
    }
    __syncthreads();
    if (tid < 64) {
        float s = ssl[tid * 4] + ssl[tid * 4 + 1] + ssl[tid * 4 + 2] + ssl[tid * 4 + 3];
        scl[tid] = 1.0f / fmaxf(sqrtf(s), 1e-12f);
    }
    __syncthreads();
    #pragma unroll
    for (int mi = 0; mi < 4; mi++)
        #pragma unroll
        for (int ni = 0; ni < 2; ni++) {
            int col = wid * 32 + ni * 16 + lm;
            if (col < HID) {
                #pragma unroll
                for (int r = 0; r < 4; r++) {
                    int rl = mi * 16 + lq * 4 + r;
                    int row = m0 + rl;
                    if (row < NN) {
                        float v = fmaxf(acc[mi][ni][r] * scl[rl], 0.f);
                        float hn = h[(size_t)row * HID + col] + v;
                        h[(size_t)row * HID + col] = hn;
                        h16[(size_t)row * 128 + col] = (_Float16)hn;
                    }
                }
            }
        }
}

__global__ void k_readout(const float* h, const int* gid,
                          const float* W1, const float* b1,
                          const float* W2, const float* b2,
                          const float* W3, const float* b3,
                          float* out) {
    __shared__ float hg[HID];
    __shared__ float y1[54];
    __shared__ float y2[27];
    __shared__ int se[2];
    int g = blockIdx.x, tid = threadIdx.x;
    if (tid < 2) {
        int key = g + tid, lo = 0, hi = NN;
        while (lo < hi) {
            int mid = (lo + hi) >> 1;
            if (gid[mid] < key) lo = mid + 1; else hi = mid;
        }
        se[tid] = lo;
    }
    __syncthreads();
    int s = se[0], e = se[1];
    if (tid < HID) {
        float acc = 0.f;
        for (int n = s; n < e; n++) acc += h[(size_t)n * HID + tid];
        int cnt = e - s;
        hg[tid] = acc / (float)((cnt > 1) ? cnt : 1);
    }
    __syncthreads();
    if (tid < 54) {
        float a = b1[tid];
        for (int k = 0; k < HID; k++) a += hg[k] * W1[k * 54 + tid];
        y1[tid] = fmaxf(a, 0.f);
    }
    __syncthreads();
    if (tid < 27) {
        float a = b2[tid];
        for (int k = 0; k < 54; k++) a += y1[k] * W2[k * 27 + tid];
        y2[tid] = fmaxf(a, 0.f);
    }
    __syncthreads();
    if (tid < 10) {
        float a = b3[tid];
        for (int k = 0; k < 27; k++) a += y2[k] * W3[k * 10 + tid];
        out[g * 10 + tid] = a;
    }
}

extern "C" void kernel_launch(void* const* d_in, const int* in_sizes, int n_in,
                              void* d_out, int out_size, void* d_ws, size_t ws_size,
                              hipStream_t stream) {
    float* out = (float*)d_out;
    (void)in_sizes; (void)n_in; (void)ws_size; (void)out_size;

    const float* feat   = (const float*)d_in[0];
    const int*   src    = (const int*)d_in[4];
    const int*   dst    = (const int*)d_in[5];
    const int*   gid    = (const int*)d_in[6];
    const float* W_emb  = (const float*)d_in[7];
    const float* b_emb  = (const float*)d_in[8];
    const float* W_pool = (const float*)d_in[9];
    const float* b_pool = (const float*)d_in[10];
    const float* W_app  = (const float*)d_in[11];
    const float* b_app  = (const float*)d_in[12];
    const float* W1     = (const float*)d_in[13];
    const float* b1     = (const float*)d_in[14];
    const float* W2     = (const float*)d_in[15];
    const float* b2     = (const float*)d_in[16];
    const float* W3     = (const float*)d_in[17];
    const float* b3     = (const float*)d_in[18];

    char* ws = (char*)d_ws;
    size_t off = 0;
    auto take = [&](size_t bytes) { char* p = ws + off; off += (bytes + 255) & ~(size_t)255; return p; };
    float*     h     = (float*)take((size_t)NN * HID * 4);
    _Float16*  h16   = (_Float16*)take((size_t)NN * 128 * 2);
    _Float16*  hp16  = (_Float16*)take((size_t)NN * 128 * 2);
    _Float16*  agg16 = (_Float16*)take((size_t)NN * 128 * 2);
    float*     part  = (float*)take((size_t)NN * 128 * 4);
    int*       cs    = (int*)take((size_t)EE * 4);
    int*       deg   = (int*)take((size_t)NN * 4);
    int*       rp    = (int*)take((size_t)(NN + 1) * 4);
    _Float16*  Bt1   = (_Float16*)take((size_t)NL * 256 * 128 * 2);
    _Float16*  Bt2   = (_Float16*)take((size_t)NL * 128 * 128 * 2);
    float*     bb1   = (float*)take((size_t)NL * 256 * 4);

    hipLaunchKernelGGL(k_zero, dim3((NN + 255) / 256), dim3(256), 0, stream, deg);
    hipLaunchKernelGGL(k_hist, dim3((EE + 255) / 256), dim3(256), 0, stream, dst, deg);
    hipLaunchKernelGGL(k_scan, dim3(1), dim3(1024), 0, stream, deg, rp);
    hipLaunchKernelGGL(k_scatter, dim3((EE + 255) / 256), dim3(256), 0, stream,
                       src, dst, rp, deg, cs);

    const int PACK_TOTAL = NL * 256 * 128 + NL * 128 * 128 + NL * 256;
    hipLaunchKernelGGL(k_pack, dim3((PACK_TOTAL + 255) / 256), dim3(256), 0, stream,
                       W_pool, b_pool, W_app, b_app, Bt1, Bt2, bb1);

    hipLaunchKernelGGL(k_embed, dim3((NN * 128 + 255) / 256), dim3(256), 0, stream,
                       feat, W_emb, b_emb, h, h16);

    for (int l = 0; l < NL; l++) {
        hipLaunchKernelGGL(k_mm1, dim3(MB, 2), dim3(256), 0, stream,
                           h16, Bt1 + (size_t)l * 256 * 128, bb1 + (size_t)l * 256,
                           hp16, part);
        hipLaunchKernelGGL(k_agg, dim3(NN), dim3(128), 0, stream, hp16, rp, cs, agg16);
        hipLaunchKernelGGL(k_mm2, dim3(MB), dim3(256), 0, stream,
                           agg16, Bt2 + (size_t)l * 128 * 128, part, h, h16);
    }
    hipLaunchKernelGGL(k_readout, dim3(GG), dim3(128), 0, stream,
                       h, gid, W1, b1, W2, b2, W3, b3, out);
}

// Round 17
// 681.693 us; speedup vs baseline: 1.1256x; 1.1256x over previous
//
#include <hip/hip_runtime.h>

#define NN 50000
#define EE 800000
#define GG 256
#define IND 32
#define HID 108
#define NL 4
#define MB 782            // ceil(50000/64) M-tiles
#define LDSK 136          // LDS B row stride in halves (272 B = 17*16, conflict-safe)
#define SCB 196           // ceil(50000/256) scan tiles

typedef __attribute__((ext_vector_type(8))) _Float16 f16x8;
typedef __attribute__((ext_vector_type(4))) float floatx4;

__global__ void k_zero(int* deg) {
    int i = blockIdx.x * 256 + threadIdx.x;
    if (i < NN) deg[i] = 0;
}

__global__ void k_hist(const int* dst, int* deg) {
    int e = blockIdx.x * 256 + threadIdx.x;
    if (e < EE) atomicAdd(&deg[dst[e]], 1);
}

// ---- 3-phase coalesced scan: deg[0..NN) -> rp[0..NN] (exclusive on rp[0]=0) ----
__global__ void k_scan_a(const int* __restrict__ deg, int* __restrict__ bsum) {
    __shared__ int ws[4];
    int b = blockIdx.x, tid = threadIdx.x;
    int i = b * 256 + tid;
    int v = (i < NN) ? deg[i] : 0;
    #pragma unroll
    for (int off = 1; off < 64; off <<= 1) v += __shfl_xor(v, off, 64);
    if ((tid & 63) == 0) ws[tid >> 6] = v;
    __syncthreads();
    if (tid == 0) bsum[b] = ws[0] + ws[1] + ws[2] + ws[3];
}

__global__ void k_scan_b(const int* __restrict__ bsum, int* __restrict__ boff) {
    __shared__ int wsum[4], wexc[4];
    int tid = threadIdx.x;
    int lane = tid & 63, wv = tid >> 6;
    int v = (tid < SCB) ? bsum[tid] : 0;
    int x = v;
    #pragma unroll
    for (int off = 1; off < 64; off <<= 1) {
        int y = __shfl_up(x, off, 64);
        if (lane >= off) x += y;
    }
    if (lane == 63) wsum[wv] = x;
    __syncthreads();
    if (tid == 0) { int run = 0; for (int w = 0; w < 4; w++) { wexc[w] = run; run += wsum[w]; } }
    __syncthreads();
    if (tid < SCB) boff[tid] = wexc[wv] + x - v;   // exclusive prefix of block sums
}

__global__ void k_scan_c(const int* __restrict__ deg, const int* __restrict__ boff,
                         int* __restrict__ rp) {
    __shared__ int wsum[4], wexc[4];
    int b = blockIdx.x, tid = threadIdx.x;
    int i = b * 256 + tid;
    int v = (i < NN) ? deg[i] : 0;
    int lane = tid & 63, wv = tid >> 6;
    int x = v;
    #pragma unroll
    for (int off = 1; off < 64; off <<= 1) {
        int y = __shfl_up(x, off, 64);
        if (lane >= off) x += y;
    }
    if (lane == 63) wsum[wv] = x;
    __syncthreads();
    if (tid == 0) { int run = 0; for (int w = 0; w < 4; w++) { wexc[w] = run; run += wsum[w]; } }
    __syncthreads();
    if (i < NN) rp[i + 1] = boff[b] + wexc[wv] + x;
    if (b == 0 && tid == 0) rp[0] = 0;
}

__global__ void k_scatter(const int* src, const int* dst, const int* rp,
                          int* deg, int* cs) {
    int e = blockIdx.x * 256 + threadIdx.x;
    if (e < EE) {
        int d = dst[e];
        int pos = atomicSub(&deg[d], 1) - 1;
        cs[rp[d] + pos] = src[e];
    }
}

// Pack weights: fp16, transposed Bt[n][k], K padded to 128.
__global__ void k_pack(const float* __restrict__ W_pool, const float* __restrict__ b_pool,
                       const float* __restrict__ W_app, const float* __restrict__ b_app,
                       _Float16* Bt1, _Float16* Bt2, float* bb1) {
    int r = blockIdx.x * 256 + threadIdx.x;
    if (r < NL * 256 * 128) {
        int l = r / (256 * 128); int t = r % (256 * 128); int n = t / 128, k = t % 128;
        float v = 0.f;
        if (k < HID) {
            if (n < HID)                        v = W_pool[((size_t)l * HID + k) * HID + n];
            else if (n >= 128 && n < 128 + HID) v = W_app[((size_t)l * 216 + k) * HID + (n - 128)];
        }
        Bt1[r] = (_Float16)v; return;
    } r -= NL * 256 * 128;
    if (r < NL * 128 * 128) {
        int l = r / (128 * 128); int t = r % (128 * 128); int n = t / 128, k = t % 128;
        float v = (n < HID && k < HID) ? W_app[((size_t)l * 216 + 108 + k) * HID + n] : 0.f;
        Bt2[r] = (_Float16)v; return;
    } r -= NL * 128 * 128;
    if (r < NL * 256) {
        int l = r / 256, n = r % 256;
        float v = 0.f;
        if (n < HID) v = b_pool[l * HID + n];
        else if (n >= 128 && n < 128 + HID) v = b_app[l * HID + (n - 128)];
        bb1[r] = v;
    }
}

// embed: h fp32 (stride 108) + h16 fp16 (stride 128, zero-padded cols)
__global__ void k_embed(const float* __restrict__ feat, const float* __restrict__ W,
                        const float* __restrict__ b,
                        float* __restrict__ h, _Float16* __restrict__ h16) {
    int i = blockIdx.x * 256 + threadIdx.x;
    if (i >= NN * 128) return;
    int n = i >> 7, c = i & 127;
    if (c < HID) {
        float acc = b[c];
        const float* fr = feat + (size_t)n * IND;
        for (int k = 0; k < IND; k++) acc += fr[k] * W[k * HID + c];
        h[(size_t)n * HID + c] = acc;
        h16[i] = (_Float16)acc;
    } else {
        h16[i] = (_Float16)0.f;
    }
}

// mm1: C[64,128] = A(h16)[64,128] @ Bt^T + bias. nt=0 -> hp16=relu fp16; nt=1 -> part fp32
__global__ __launch_bounds__(256)
void k_mm1(const _Float16* __restrict__ A, const _Float16* __restrict__ Bt,
           const float* __restrict__ bias,
           _Float16* __restrict__ hp16, float* __restrict__ part) {
    __shared__ _Float16 Bl[128 * LDSK];
    int tid = threadIdx.x;
    int nt = blockIdx.y;
    const _Float16* Bsrc = Bt + (size_t)nt * 128 * 128;
    for (int i = tid; i < 128 * 16; i += 256) {
        int rr = i >> 4, g = i & 15;
        *(uint4*)&Bl[rr * LDSK + g * 8] = *(const uint4*)(Bsrc + rr * 128 + g * 8);
    }
    __syncthreads();
    int lane = tid & 63, wid = tid >> 6, lm = lane & 15, lq = lane >> 4;
    int m0 = blockIdx.x * 64;
    floatx4 acc[4][2];
    #pragma unroll
    for (int mi = 0; mi < 4; mi++)
        #pragma unroll
        for (int ni = 0; ni < 2; ni++) { floatx4 z = {0.f,0.f,0.f,0.f}; acc[mi][ni] = z; }
    f16x8 zf = {(_Float16)0, (_Float16)0, (_Float16)0, (_Float16)0,
                (_Float16)0, (_Float16)0, (_Float16)0, (_Float16)0};
    #pragma unroll
    for (int ks = 0; ks < 4; ks++) {
        f16x8 a[4], b[2];
        #pragma unroll
        for (int mi = 0; mi < 4; mi++) {
            int row = m0 + mi * 16 + lm;
            a[mi] = (row < NN) ? *(const f16x8*)(A + (size_t)row * 128 + ks * 32 + lq * 8) : zf;
        }
        #pragma unroll
        for (int ni = 0; ni < 2; ni++)
            b[ni] = *(const f16x8*)&Bl[(wid * 32 + ni * 16 + lm) * LDSK + ks * 32 + lq * 8];
        #pragma unroll
        for (int mi = 0; mi < 4; mi++)
            #pragma unroll
            for (int ni = 0; ni < 2; ni++)
                acc[mi][ni] = __builtin_amdgcn_mfma_f32_16x16x32_f16(a[mi], b[ni], acc[mi][ni], 0, 0, 0);
    }
    #pragma unroll
    for (int mi = 0; mi < 4; mi++)
        #pragma unroll
        for (int ni = 0; ni < 2; ni++) {
            int col = wid * 32 + ni * 16 + lm;
            float bc = bias[nt * 128 + col];
            #pragma unroll
            for (int r = 0; r < 4; r++) {
                int row = m0 + mi * 16 + lq * 4 + r;
                if (row < NN) {
                    float v = acc[mi][ni][r] + bc;
                    if (nt == 0) hp16[(size_t)row * 128 + col] = (_Float16)fmaxf(v, 0.f);
                    else         part[(size_t)row * 128 + col] = v;
                }
            }
        }
}

// agg16[n][:] = fp16(mean over in-neighbors of hp16)
__global__ __launch_bounds__(128)
void k_agg(const _Float16* __restrict__ hp16, const int* __restrict__ rp,
           const int* __restrict__ cs, _Float16* __restrict__ agg16) {
    __shared__ float asl[8][128];
    int n = blockIdx.x, tid = threadIdx.x;
    int t = tid & 15, q = tid >> 4;
    int s0 = rp[n], s1 = rp[n + 1];
    float a[8];
    #pragma unroll
    for (int j = 0; j < 8; j++) a[j] = 0.f;
    int co = t * 8;
    for (int e = s0 + q; e < s1; e += 8) {
        f16x8 v = *(const f16x8*)(hp16 + (size_t)cs[e] * 128 + co);
        #pragma unroll
        for (int j = 0; j < 8; j++) a[j] += (float)v[j];
    }
    #pragma unroll
    for (int j = 0; j < 8; j++) asl[q][co + j] = a[j];
    __syncthreads();
    int col = tid;
    float s = 0.f;
    #pragma unroll
    for (int qq = 0; qq < 8; qq++) s += asl[qq][col];
    int dg = s1 - s0;
    float inv = 1.0f / (float)((dg > 1) ? dg : 1);
    agg16[(size_t)n * 128 + col] = (_Float16)(s * inv);
}

// mm2: bu = agg16 @ Bt2^T + part; l2norm -> relu -> h += ; write h fp32 + h16
__global__ __launch_bounds__(256)
void k_mm2(const _Float16* __restrict__ A, const _Float16* __restrict__ Bt,
           const float* __restrict__ part,
           float* __restrict__ h, _Float16* __restrict__ h16) {
    __shared__ _Float16 Bl[128 * LDSK];
    __shared__ float ssl[64 * 4];
    __shared__ float scl[64];
    int tid = threadIdx.x;
    for (int i = tid; i < 128 * 16; i += 256) {
        int rr = i >> 4, g = i & 15;
        *(uint4*)&Bl[rr * LDSK + g * 8] = *(const uint4*)(Bt + rr * 128 + g * 8);
    }
    __syncthreads();
    int lane = tid & 63, wid = tid >> 6, lm = lane & 15, lq = lane >> 4;
    int m0 = blockIdx.x * 64;
    floatx4 acc[4][2];
    #pragma unroll
    for (int mi = 0; mi < 4; mi++)
        #pragma unroll
        for (int ni = 0; ni < 2; ni++) { floatx4 z = {0.f,0.f,0.f,0.f}; acc[mi][ni] = z; }
    f16x8 zf = {(_Float16)0, (_Float16)0, (_Float16)0, (_Float16)0,
                (_Float16)0, (_Float16)0, (_Float16)0, (_Float16)0};
    #pragma unroll
    for (int ks = 0; ks < 4; ks++) {
        f16x8 a[4], b[2];
        #pragma unroll
        for (int mi = 0; mi < 4; mi++) {
            int row = m0 + mi * 16 + lm;
            a[mi] = (row < NN) ? *(const f16x8*)(A + (size_t)row * 128 + ks * 32 + lq * 8) : zf;
        }
        #pragma unroll
        for (int ni = 0; ni < 2; ni++)
            b[ni] = *(const f16x8*)&Bl[(wid * 32 + ni * 16 + lm) * LDSK + ks * 32 + lq * 8];
        #pragma unroll
        for (int mi = 0; mi < 4; mi++)
            #pragma unroll
            for (int ni = 0; ni < 2; ni++)
                acc[mi][ni] = __builtin_amdgcn_mfma_f32_16x16x32_f16(a[mi], b[ni], acc[mi][ni], 0, 0, 0);
    }
    #pragma unroll
    for (int mi = 0; mi < 4; mi++)
        #pragma unroll
        for (int ni = 0; ni < 2; ni++) {
            int col = wid * 32 + ni * 16 + lm;
            #pragma unroll
            for (int r = 0; r < 4; r++) {
                int row = m0 + mi * 16 + lq * 4 + r;
                acc[mi][ni][r] = (row < NN) ? acc[mi][ni][r] + part[(size_t)row * 128 + col] : 0.f;
            }
        }
    float ss[4][4];
    #pragma unroll
    for (int mi = 0; mi < 4; mi++)
        #pragma unroll
        for (int r = 0; r < 4; r++)
            ss[mi][r] = acc[mi][0][r] * acc[mi][0][r] + acc[mi][1][r] * acc[mi][1][r];
    #pragma unroll
    for (int off = 1; off < 16; off <<= 1)
        #pragma unroll
        for (int mi = 0; mi < 4; mi++)
            #pragma unroll
            for (int r = 0; r < 4; r++)
                ss[mi][r] += __shfl_xor(ss[mi][r], off, 64);
    if (lm == 0) {
        #pragma unroll
        for (int mi = 0; mi < 4; mi++)
            #pragma unroll
            for (int r = 0; r < 4; r++)
                ssl[(mi * 16 + lq * 4 + r) * 4 + wid] = ss[mi][r];
    }
    __syncthreads();
    if (tid < 64) {
        float s = ssl[tid * 4] + ssl[tid * 4 + 1] + ssl[tid * 4 + 2] + ssl[tid * 4 + 3];
        scl[tid] = 1.0f / fmaxf(sqrtf(s), 1e-12f);
    }
    __syncthreads();
    #pragma unroll
    for (int mi = 0; mi < 4; mi++)
        #pragma unroll
        for (int ni = 0; ni < 2; ni++) {
            int col = wid * 32 + ni * 16 + lm;
            if (col < HID) {
                #pragma unroll
                for (int r = 0; r < 4; r++) {
                    int rl = mi * 16 + lq * 4 + r;
                    int row = m0 + rl;
                    if (row < NN) {
                        float v = fmaxf(acc[mi][ni][r] * scl[rl], 0.f);
                        float hn = h[(size_t)row * HID + col] + v;
                        h[(size_t)row * HID + col] = hn;
                        h16[(size_t)row * 128 + col] = (_Float16)hn;
                    }
                }
            }
        }
}

__global__ void k_readout(const float* h, const int* gid,
                          const float* W1, const float* b1,
                          const float* W2, const float* b2,
                          const float* W3, const float* b3,
                          float* out) {
    __shared__ float hg[HID];
    __shared__ float y1[54];
    __shared__ float y2[27];
    __shared__ int se[2];
    int g = blockIdx.x, tid = threadIdx.x;
    if (tid < 2) {
        int key = g + tid, lo = 0, hi = NN;
        while (lo < hi) {
            int mid = (lo + hi) >> 1;
            if (gid[mid] < key) lo = mid + 1; else hi = mid;
        }
        se[tid] = lo;
    }
    __syncthreads();
    int s = se[0], e = se[1];
    if (tid < HID) {
        float acc = 0.f;
        for (int n = s; n < e; n++) acc += h[(size_t)n * HID + tid];
        int cnt = e - s;
        hg[tid] = acc / (float)((cnt > 1) ? cnt : 1);
    }
    __syncthreads();
    if (tid < 54) {
        float a = b1[tid];
        for (int k = 0; k < HID; k++) a += hg[k] * W1[k * 54 + tid];
        y1[tid] = fmaxf(a, 0.f);
    }
    __syncthreads();
    if (tid < 27) {
        float a = b2[tid];
        for (int k = 0; k < 54; k++) a += y1[k] * W2[k * 27 + tid];
        y2[tid] = fmaxf(a, 0.f);
    }
    __syncthreads();
    if (tid < 10) {
        float a = b3[tid];
        for (int k = 0; k < 27; k++) a += y2[k] * W3[k * 10 + tid];
        out[g * 10 + tid] = a;
    }
}

extern "C" void kernel_launch(void* const* d_in, const int* in_sizes, int n_in,
                              void* d_out, int out_size, void* d_ws, size_t ws_size,
                              hipStream_t stream) {
    float* out = (float*)d_out;
    (void)in_sizes; (void)n_in; (void)ws_size; (void)out_size;

    const float* feat   = (const float*)d_in[0];
    const int*   src    = (const int*)d_in[4];
    const int*   dst    = (const int*)d_in[5];
    const int*   gid    = (const int*)d_in[6];
    const float* W_emb  = (const float*)d_in[7];
    const float* b_emb  = (const float*)d_in[8];
    const float* W_pool = (const float*)d_in[9];
    const float* b_pool = (const float*)d_in[10];
    const float* W_app  = (const float*)d_in[11];
    const float* b_app  = (const float*)d_in[12];
    const float* W1     = (const float*)d_in[13];
    const float* b1     = (const float*)d_in[14];
    const float* W2     = (const float*)d_in[15];
    const float* b2     = (const float*)d_in[16];
    const float* W3     = (const float*)d_in[17];
    const float* b3     = (const float*)d_in[18];

    char* ws = (char*)d_ws;
    size_t off = 0;
    auto take = [&](size_t bytes) { char* p = ws + off; off += (bytes + 255) & ~(size_t)255; return p; };
    float*     h     = (float*)take((size_t)NN * HID * 4);
    _Float16*  h16   = (_Float16*)take((size_t)NN * 128 * 2);
    _Float16*  hp16  = (_Float16*)take((size_t)NN * 128 * 2);
    _Float16*  agg16 = (_Float16*)take((size_t)NN * 128 * 2);
    float*     part  = (float*)take((size_t)NN * 128 * 4);
    int*       cs    = (int*)take((size_t)EE * 4);
    int*       deg   = (int*)take((size_t)NN * 4);
    int*       rp    = (int*)take((size_t)(NN + 1) * 4);
    int*       bsum  = (int*)take((size_t)SCB * 4);
    int*       boff  = (int*)take((size_t)SCB * 4);
    _Float16*  Bt1   = (_Float16*)take((size_t)NL * 256 * 128 * 2);
    _Float16*  Bt2   = (_Float16*)take((size_t)NL * 128 * 128 * 2);
    float*     bb1   = (float*)take((size_t)NL * 256 * 4);

    hipLaunchKernelGGL(k_zero, dim3((NN + 255) / 256), dim3(256), 0, stream, deg);
    hipLaunchKernelGGL(k_hist, dim3((EE + 255) / 256), dim3(256), 0, stream, dst, deg);
    hipLaunchKernelGGL(k_scan_a, dim3(SCB), dim3(256), 0, stream, deg, bsum);
    hipLaunchKernelGGL(k_scan_b, dim3(1), dim3(256), 0, stream, bsum, boff);
    hipLaunchKernelGGL(k_scan_c, dim3(SCB), dim3(256), 0, stream, deg, boff, rp);
    hipLaunchKernelGGL(k_scatter, dim3((EE + 255) / 256), dim3(256), 0, stream,
                       src, dst, rp, deg, cs);

    const int PACK_TOTAL = NL * 256 * 128 + NL * 128 * 128 + NL * 256;
    hipLaunchKernelGGL(k_pack, dim3((PACK_TOTAL + 255) / 256), dim3(256), 0, stream,
                       W_pool, b_pool, W_app, b_app, Bt1, Bt2, bb1);

    hipLaunchKernelGGL(k_embed, dim3((NN * 128 + 255) / 256), dim3(256), 0, stream,
                       feat, W_emb, b_emb, h, h16);

    for (int l = 0; l < NL; l++) {
        hipLaunchKernelGGL(k_mm1, dim3(MB, 2), dim3(256), 0, stream,
                           h16, Bt1 + (size_t)l * 256 * 128, bb1 + (size_t)l * 256,
                           hp16, part);
        hipLaunchKernelGGL(k_agg, dim3(NN), dim3(128), 0, stream, hp16, rp, cs, agg16);
        hipLaunchKernelGGL(k_mm2, dim3(MB), dim3(256), 0, stream,
                           agg16, Bt2 + (size_t)l * 128 * 128, part, h, h16);
    }
    hipLaunchKernelGGL(k_readout, dim3(GG), dim3(128), 0, stream,
                       h, gid, W1, b1, W2, b2, W3, b3, out);
}

// Round 18
// 649.500 us; speedup vs baseline: 1.1814x; 1.0496x over previous
//
#include <hip/hip_runtime.h>

#define NN 50000
#define EE 800000
#define GG 256
#define IND 32
#define HID 108
#define NL 4
#define MB 782            // ceil(50000/64) M-tiles
#define LDSK 136          // LDS B row stride in halves (272 B = 17*16, conflict-safe)
#define SCB 196           // ceil(50000/256) scan tiles
#define RS 8              // readout slices per graph

typedef __attribute__((ext_vector_type(8))) _Float16 f16x8;
typedef __attribute__((ext_vector_type(4))) float floatx4;

__global__ void k_zero(int* deg) {
    int i = blockIdx.x * 256 + threadIdx.x;
    if (i < NN) deg[i] = 0;
}

__global__ void k_hist(const int* dst, int* deg) {
    int e = blockIdx.x * 256 + threadIdx.x;
    if (e < EE) atomicAdd(&deg[dst[e]], 1);
}

// ---- 3-phase coalesced scan ----
__global__ void k_scan_a(const int* __restrict__ deg, int* __restrict__ bsum) {
    __shared__ int ws[4];
    int b = blockIdx.x, tid = threadIdx.x;
    int i = b * 256 + tid;
    int v = (i < NN) ? deg[i] : 0;
    #pragma unroll
    for (int off = 1; off < 64; off <<= 1) v += __shfl_xor(v, off, 64);
    if ((tid & 63) == 0) ws[tid >> 6] = v;
    __syncthreads();
    if (tid == 0) bsum[b] = ws[0] + ws[1] + ws[2] + ws[3];
}

__global__ void k_scan_b(const int* __restrict__ bsum, int* __restrict__ boff) {
    __shared__ int wsum[4], wexc[4];
    int tid = threadIdx.x;
    int lane = tid & 63, wv = tid >> 6;
    int v = (tid < SCB) ? bsum[tid] : 0;
    int x = v;
    #pragma unroll
    for (int off = 1; off < 64; off <<= 1) {
        int y = __shfl_up(x, off, 64);
        if (lane >= off) x += y;
    }
    if (lane == 63) wsum[wv] = x;
    __syncthreads();
    if (tid == 0) { int run = 0; for (int w = 0; w < 4; w++) { wexc[w] = run; run += wsum[w]; } }
    __syncthreads();
    if (tid < SCB) boff[tid] = wexc[wv] + x - v;
}

__global__ void k_scan_c(const int* __restrict__ deg, const int* __restrict__ boff,
                         int* __restrict__ rp) {
    __shared__ int wsum[4], wexc[4];
    int b = blockIdx.x, tid = threadIdx.x;
    int i = b * 256 + tid;
    int v = (i < NN) ? deg[i] : 0;
    int lane = tid & 63, wv = tid >> 6;
    int x = v;
    #pragma unroll
    for (int off = 1; off < 64; off <<= 1) {
        int y = __shfl_up(x, off, 64);
        if (lane >= off) x += y;
    }
    if (lane == 63) wsum[wv] = x;
    __syncthreads();
    if (tid == 0) { int run = 0; for (int w = 0; w < 4; w++) { wexc[w] = run; run += wsum[w]; } }
    __syncthreads();
    if (i < NN) rp[i + 1] = boff[b] + wexc[wv] + x;
    if (b == 0 && tid == 0) rp[0] = 0;
}

__global__ void k_scatter(const int* src, const int* dst, const int* rp,
                          int* deg, int* cs) {
    int e = blockIdx.x * 256 + threadIdx.x;
    if (e < EE) {
        int d = dst[e];
        int pos = atomicSub(&deg[d], 1) - 1;
        cs[rp[d] + pos] = src[e];
    }
}

// Pack weights: fp16, transposed Bt[n][k], K padded to 128.
__global__ void k_pack(const float* __restrict__ W_pool, const float* __restrict__ b_pool,
                       const float* __restrict__ W_app, const float* __restrict__ b_app,
                       _Float16* Bt1, _Float16* Bt2, float* bb1) {
    int r = blockIdx.x * 256 + threadIdx.x;
    if (r < NL * 256 * 128) {
        int l = r / (256 * 128); int t = r % (256 * 128); int n = t / 128, k = t % 128;
        float v = 0.f;
        if (k < HID) {
            if (n < HID)                        v = W_pool[((size_t)l * HID + k) * HID + n];
            else if (n >= 128 && n < 128 + HID) v = W_app[((size_t)l * 216 + k) * HID + (n - 128)];
        }
        Bt1[r] = (_Float16)v; return;
    } r -= NL * 256 * 128;
    if (r < NL * 128 * 128) {
        int l = r / (128 * 128); int t = r % (128 * 128); int n = t / 128, k = t % 128;
        float v = (n < HID && k < HID) ? W_app[((size_t)l * 216 + 108 + k) * HID + n] : 0.f;
        Bt2[r] = (_Float16)v; return;
    } r -= NL * 128 * 128;
    if (r < NL * 256) {
        int l = r / 256, n = r % 256;
        float v = 0.f;
        if (n < HID) v = b_pool[l * HID + n];
        else if (n >= 128 && n < 128 + HID) v = b_app[l * HID + (n - 128)];
        bb1[r] = v;
    }
}

// embed: h fp32 (stride 108) + h16 fp16 (stride 128, zero-padded cols)
__global__ void k_embed(const float* __restrict__ feat, const float* __restrict__ W,
                        const float* __restrict__ b,
                        float* __restrict__ h, _Float16* __restrict__ h16) {
    int i = blockIdx.x * 256 + threadIdx.x;
    if (i >= NN * 128) return;
    int n = i >> 7, c = i & 127;
    if (c < HID) {
        float acc = b[c];
        const float* fr = feat + (size_t)n * IND;
        for (int k = 0; k < IND; k++) acc += fr[k] * W[k * HID + c];
        h[(size_t)n * HID + c] = acc;
        h16[i] = (_Float16)acc;
    } else {
        h16[i] = (_Float16)0.f;
    }
}

// mm1: C[64,128] = A(h16)[64,128] @ Bt^T + bias. nt=0 -> hp16=relu fp16; nt=1 -> part fp32
__global__ __launch_bounds__(256)
void k_mm1(const _Float16* __restrict__ A, const _Float16* __restrict__ Bt,
           const float* __restrict__ bias,
           _Float16* __restrict__ hp16, float* __restrict__ part) {
    __shared__ _Float16 Bl[128 * LDSK];
    int tid = threadIdx.x;
    int nt = blockIdx.y;
    const _Float16* Bsrc = Bt + (size_t)nt * 128 * 128;
    for (int i = tid; i < 128 * 16; i += 256) {
        int rr = i >> 4, g = i & 15;
        *(uint4*)&Bl[rr * LDSK + g * 8] = *(const uint4*)(Bsrc + rr * 128 + g * 8);
    }
    __syncthreads();
    int lane = tid & 63, wid = tid >> 6, lm = lane & 15, lq = lane >> 4;
    int m0 = blockIdx.x * 64;
    floatx4 acc[4][2];
    #pragma unroll
    for (int mi = 0; mi < 4; mi++)
        #pragma unroll
        for (int ni = 0; ni < 2; ni++) { floatx4 z = {0.f,0.f,0.f,0.f}; acc[mi][ni] = z; }
    f16x8 zf = {(_Float16)0, (_Float16)0, (_Float16)0, (_Float16)0,
                (_Float16)0, (_Float16)0, (_Float16)0, (_Float16)0};
    #pragma unroll
    for (int ks = 0; ks < 4; ks++) {
        f16x8 a[4], b[2];
        #pragma unroll
        for (int mi = 0; mi < 4; mi++) {
            int row = m0 + mi * 16 + lm;
            a[mi] = (row < NN) ? *(const f16x8*)(A + (size_t)row * 128 + ks * 32 + lq * 8) : zf;
        }
        #pragma unroll
        for (int ni = 0; ni < 2; ni++)
            b[ni] = *(const f16x8*)&Bl[(wid * 32 + ni * 16 + lm) * LDSK + ks * 32 + lq * 8];
        #pragma unroll
        for (int mi = 0; mi < 4; mi++)
            #pragma unroll
            for (int ni = 0; ni < 2; ni++)
                acc[mi][ni] = __builtin_amdgcn_mfma_f32_16x16x32_f16(a[mi], b[ni], acc[mi][ni], 0, 0, 0);
    }
    #pragma unroll
    for (int mi = 0; mi < 4; mi++)
        #pragma unroll
        for (int ni = 0; ni < 2; ni++) {
            int col = wid * 32 + ni * 16 + lm;
            float bc = bias[nt * 128 + col];
            #pragma unroll
            for (int r = 0; r < 4; r++) {
                int row = m0 + mi * 16 + lq * 4 + r;
                if (row < NN) {
                    float v = acc[mi][ni][r] + bc;
                    if (nt == 0) hp16[(size_t)row * 128 + col] = (_Float16)fmaxf(v, 0.f);
                    else         part[(size_t)row * 128 + col] = v;
                }
            }
        }
}

// agg16[n][:] = fp16(mean over in-neighbors of hp16)
__global__ __launch_bounds__(128)
void k_agg(const _Float16* __restrict__ hp16, const int* __restrict__ rp,
           const int* __restrict__ cs, _Float16* __restrict__ agg16) {
    __shared__ float asl[8][128];
    int n = blockIdx.x, tid = threadIdx.x;
    int t = tid & 15, q = tid >> 4;
    int s0 = rp[n], s1 = rp[n + 1];
    float a[8];
    #pragma unroll
    for (int j = 0; j < 8; j++) a[j] = 0.f;
    int co = t * 8;
    for (int e = s0 + q; e < s1; e += 8) {
        f16x8 v = *(const f16x8*)(hp16 + (size_t)cs[e] * 128 + co);
        #pragma unroll
        for (int j = 0; j < 8; j++) a[j] += (float)v[j];
    }
    #pragma unroll
    for (int j = 0; j < 8; j++) asl[q][co + j] = a[j];
    __syncthreads();
    int col = tid;
    float s = 0.f;
    #pragma unroll
    for (int qq = 0; qq < 8; qq++) s += asl[qq][col];
    int dg = s1 - s0;
    float inv = 1.0f / (float)((dg > 1) ? dg : 1);
    agg16[(size_t)n * 128 + col] = (_Float16)(s * inv);
}

// mm2: bu = agg16 @ Bt2^T + part; l2norm -> relu -> h += ; write h fp32 + h16
__global__ __launch_bounds__(256)
void k_mm2(const _Float16* __restrict__ A, const _Float16* __restrict__ Bt,
           const float* __restrict__ part,
           float* __restrict__ h, _Float16* __restrict__ h16) {
    __shared__ _Float16 Bl[128 * LDSK];
    __shared__ float ssl[64 * 4];
    __shared__ float scl[64];
    int tid = threadIdx.x;
    for (int i = tid; i < 128 * 16; i += 256) {
        int rr = i >> 4, g = i & 15;
        *(uint4*)&Bl[rr * LDSK + g * 8] = *(const uint4*)(Bt + rr * 128 + g * 8);
    }
    __syncthreads();
    int lane = tid & 63, wid = tid >> 6, lm = lane & 15, lq = lane >> 4;
    int m0 = blockIdx.x * 64;
    floatx4 acc[4][2];
    #pragma unroll
    for (int mi = 0; mi < 4; mi++)
        #pragma unroll
        for (int ni = 0; ni < 2; ni++) { floatx4 z = {0.f,0.f,0.f,0.f}; acc[mi][ni] = z; }
    f16x8 zf = {(_Float16)0, (_Float16)0, (_Float16)0, (_Float16)0,
                (_Float16)0, (_Float16)0, (_Float16)0, (_Float16)0};
    #pragma unroll
    for (int ks = 0; ks < 4; ks++) {
        f16x8 a[4], b[2];
        #pragma unroll
        for (int mi = 0; mi < 4; mi++) {
            int row = m0 + mi * 16 + lm;
            a[mi] = (row < NN) ? *(const f16x8*)(A + (size_t)row * 128 + ks * 32 + lq * 8) : zf;
        }
        #pragma unroll
        for (int ni = 0; ni < 2; ni++)
            b[ni] = *(const f16x8*)&Bl[(wid * 32 + ni * 16 + lm) * LDSK + ks * 32 + lq * 8];
        #pragma unroll
        for (int mi = 0; mi < 4; mi++)
            #pragma unroll
            for (int ni = 0; ni < 2; ni++)
                acc[mi][ni] = __builtin_amdgcn_mfma_f32_16x16x32_f16(a[mi], b[ni], acc[mi][ni], 0, 0, 0);
    }
    #pragma unroll
    for (int mi = 0; mi < 4; mi++)
        #pragma unroll
        for (int ni = 0; ni < 2; ni++) {
            int col = wid * 32 + ni * 16 + lm;
            #pragma unroll
            for (int r = 0; r < 4; r++) {
                int row = m0 + mi * 16 + lq * 4 + r;
                acc[mi][ni][r] = (row < NN) ? acc[mi][ni][r] + part[(size_t)row * 128 + col] : 0.f;
            }
        }
    float ss[4][4];
    #pragma unroll
    for (int mi = 0; mi < 4; mi++)
        #pragma unroll
        for (int r = 0; r < 4; r++)
            ss[mi][r] = acc[mi][0][r] * acc[mi][0][r] + acc[mi][1][r] * acc[mi][1][r];
    #pragma unroll
    for (int off = 1; off < 16; off <<= 1)
        #pragma unroll
        for (int mi = 0; mi < 4; mi++)
            #pragma unroll
            for (int r = 0; r < 4; r++)
                ss[mi][r] += __shfl_xor(ss[mi][r], off, 64);
    if (lm == 0) {
        #pragma unroll
        for (int mi = 0; mi < 4; mi++)
            #pragma unroll
            for (int r = 0; r < 4; r++)
                ssl[(mi * 16 + lq * 4 + r) * 4 + wid] = ss[mi][r];
    }
    __syncthreads();
    if (tid < 64) {
        float s = ssl[tid * 4] + ssl[tid * 4 + 1] + ssl[tid * 4 + 2] + ssl[tid * 4 + 3];
        scl[tid] = 1.0f / fmaxf(sqrtf(s), 1e-12f);
    }
    __syncthreads();
    #pragma unroll
    for (int mi = 0; mi < 4; mi++)
        #pragma unroll
        for (int ni = 0; ni < 2; ni++) {
            int col = wid * 32 + ni * 16 + lm;
            if (col < HID) {
                #pragma unroll
                for (int r = 0; r < 4; r++) {
                    int rl = mi * 16 + lq * 4 + r;
                    int row = m0 + rl;
                    if (row < NN) {
                        float v = fmaxf(acc[mi][ni][r] * scl[rl], 0.f);
                        float hn = h[(size_t)row * HID + col] + v;
                        h[(size_t)row * HID + col] = hn;
                        h16[(size_t)row * 128 + col] = (_Float16)hn;
                    }
                }
            }
        }
}

// readout phase 1: per-(graph, slice) partial column sums of h
__global__ __launch_bounds__(128)
void k_seg(const float* __restrict__ h, const int* __restrict__ gid,
           float* __restrict__ hgp) {
    __shared__ int se[2];
    int g = blockIdx.x, sl = blockIdx.y, tid = threadIdx.x;
    if (tid < 2) {
        int key = g + tid, lo = 0, hi = NN;
        while (lo < hi) {
            int mid = (lo + hi) >> 1;
            if (gid[mid] < key) lo = mid + 1; else hi = mid;
        }
        se[tid] = lo;
    }
    __syncthreads();
    int s = se[0], e = se[1];
    int cnt = e - s;
    int chunk = (cnt + RS - 1) / RS;
    int ls = s + sl * chunk;
    int le = min(e, ls + chunk);
    if (tid < HID) {
        float acc = 0.f;
        for (int n = ls; n < le; n++) acc += h[(size_t)n * HID + tid];
        hgp[((size_t)g * RS + sl) * HID + tid] = acc;
    }
}

// readout phase 2: combine partials, mean, 3-layer MLP
__global__ __launch_bounds__(128)
void k_mlp(const float* __restrict__ hgp, const int* __restrict__ gid,
           const float* __restrict__ W1, const float* __restrict__ b1,
           const float* __restrict__ W2, const float* __restrict__ b2,
           const float* __restrict__ W3, const float* __restrict__ b3,
           float* __restrict__ out) {
    __shared__ float hg[HID];
    __shared__ float y1[54];
    __shared__ float y2[27];
    __shared__ int se[2];
    int g = blockIdx.x, tid = threadIdx.x;
    if (tid < 2) {
        int key = g + tid, lo = 0, hi = NN;
        while (lo < hi) {
            int mid = (lo + hi) >> 1;
            if (gid[mid] < key) lo = mid + 1; else hi = mid;
        }
        se[tid] = lo;
    }
    __syncthreads();
    int cnt = se[1] - se[0];
    if (tid < HID) {
        float acc = 0.f;
        #pragma unroll
        for (int sl = 0; sl < RS; sl++) acc += hgp[((size_t)g * RS + sl) * HID + tid];
        hg[tid] = acc / (float)((cnt > 1) ? cnt : 1);
    }
    __syncthreads();
    if (tid < 54) {
        float a = b1[tid];
        for (int k = 0; k < HID; k++) a += hg[k] * W1[k * 54 + tid];
        y1[tid] = fmaxf(a, 0.f);
    }
    __syncthreads();
    if (tid < 27) {
        float a = b2[tid];
        for (int k = 0; k < 54; k++) a += y1[k] * W2[k * 27 + tid];
        y2[tid] = fmaxf(a, 0.f);
    }
    __syncthreads();
    if (tid < 10) {
        float a = b3[tid];
        for (int k = 0; k < 27; k++) a += y2[k] * W3[k * 10 + tid];
        out[g * 10 + tid] = a;
    }
}

extern "C" void kernel_launch(void* const* d_in, const int* in_sizes, int n_in,
                              void* d_out, int out_size, void* d_ws, size_t ws_size,
                              hipStream_t stream) {
    float* out = (float*)d_out;
    (void)in_sizes; (void)n_in; (void)ws_size; (void)out_size;

    const float* feat   = (const float*)d_in[0];
    const int*   src    = (const int*)d_in[4];
    const int*   dst    = (const int*)d_in[5];
    const int*   gid    = (const int*)d_in[6];
    const float* W_emb  = (const float*)d_in[7];
    const float* b_emb  = (const float*)d_in[8];
    const float* W_pool = (const float*)d_in[9];
    const float* b_pool = (const float*)d_in[10];
    const float* W_app  = (const float*)d_in[11];
    const float* b_app  = (const float*)d_in[12];
    const float* W1     = (const float*)d_in[13];
    const float* b1     = (const float*)d_in[14];
    const float* W2     = (const float*)d_in[15];
    const float* b2     = (const float*)d_in[16];
    const float* W3     = (const float*)d_in[17];
    const float* b3     = (const float*)d_in[18];

    char* ws = (char*)d_ws;
    size_t off = 0;
    auto take = [&](size_t bytes) { char* p = ws + off; off += (bytes + 255) & ~(size_t)255; return p; };
    float*     h     = (float*)take((size_t)NN * HID * 4);
    _Float16*  h16   = (_Float16*)take((size_t)NN * 128 * 2);
    _Float16*  hp16  = (_Float16*)take((size_t)NN * 128 * 2);
    _Float16*  agg16 = (_Float16*)take((size_t)NN * 128 * 2);
    float*     part  = (float*)take((size_t)NN * 128 * 4);
    int*       cs    = (int*)take((size_t)EE * 4);
    int*       deg   = (int*)take((size_t)NN * 4);
    int*       rp    = (int*)take((size_t)(NN + 1) * 4);
    int*       bsum  = (int*)take((size_t)SCB * 4);
    int*       boff  = (int*)take((size_t)SCB * 4);
    float*     hgp   = (float*)take((size_t)GG * RS * HID * 4);
    _Float16*  Bt1   = (_Float16*)take((size_t)NL * 256 * 128 * 2);
    _Float16*  Bt2   = (_Float16*)take((size_t)NL * 128 * 128 * 2);
    float*     bb1   = (float*)take((size_t)NL * 256 * 4);

    hipLaunchKernelGGL(k_zero, dim3((NN + 255) / 256), dim3(256), 0, stream, deg);
    hipLaunchKernelGGL(k_hist, dim3((EE + 255) / 256), dim3(256), 0, stream, dst, deg);
    hipLaunchKernelGGL(k_scan_a, dim3(SCB), dim3(256), 0, stream, deg, bsum);
    hipLaunchKernelGGL(k_scan_b, dim3(1), dim3(256), 0, stream, bsum, boff);
    hipLaunchKernelGGL(k_scan_c, dim3(SCB), dim3(256), 0, stream, deg, boff, rp);
    hipLaunchKernelGGL(k_scatter, dim3((EE + 255) / 256), dim3(256), 0, stream,
                       src, dst, rp, deg, cs);

    const int PACK_TOTAL = NL * 256 * 128 + NL * 128 * 128 + NL * 256;
    hipLaunchKernelGGL(k_pack, dim3((PACK_TOTAL + 255) / 256), dim3(256), 0, stream,
                       W_pool, b_pool, W_app, b_app, Bt1, Bt2, bb1);

    hipLaunchKernelGGL(k_embed, dim3((NN * 128 + 255) / 256), dim3(256), 0, stream,
                       feat, W_emb, b_emb, h, h16);

    for (int l = 0; l < NL; l++) {
        hipLaunchKernelGGL(k_mm1, dim3(MB, 2), dim3(256), 0, stream,
                           h16, Bt1 + (size_t)l * 256 * 128, bb1 + (size_t)l * 256,
                           hp16, part);
        hipLaunchKernelGGL(k_agg, dim3(NN), dim3(128), 0, stream, hp16, rp, cs, agg16);
        hipLaunchKernelGGL(k_mm2, dim3(MB), dim3(256), 0, stream,
                           agg16, Bt2 + (size_t)l * 128 * 128, part, h, h16);
    }
    hipLaunchKernelGGL(k_seg, dim3(GG, RS), dim3(128), 0, stream, h, gid, hgp);
    hipLaunchKernelGGL(k_mlp, dim3(GG), dim3(128), 0, stream,
                       hgp, gid, W1, b1, W2, b2, W3, b3, out);
}

// Round 19
// 610.739 us; speedup vs baseline: 1.2564x; 1.0635x over previous
//
#include <hip/hip_runtime.h>

#define NN 50000
#define EE 800000
#define GG 256
#define IND 32
#define HID 108
#define NL 4
#define MB 782            // ceil(50000/64) M-tiles
#define LDSK 136          // LDS B row stride in halves (272 B = 17*16, conflict-safe)
#define SCB 196           // ceil(50000/256) scan tiles
#define RS 8              // readout slices per graph

typedef __attribute__((ext_vector_type(8))) _Float16 f16x8;
typedef __attribute__((ext_vector_type(4))) float floatx4;

__global__ void k_zero(int* deg) {
    int i = blockIdx.x * 256 + threadIdx.x;
    if (i < NN) deg[i] = 0;
}

__global__ void k_hist(const int* dst, int* deg) {
    int e = blockIdx.x * 256 + threadIdx.x;
    if (e < EE) atomicAdd(&deg[dst[e]], 1);
}

// ---- 3-phase coalesced scan ----
__global__ void k_scan_a(const int* __restrict__ deg, int* __restrict__ bsum) {
    __shared__ int ws[4];
    int b = blockIdx.x, tid = threadIdx.x;
    int i = b * 256 + tid;
    int v = (i < NN) ? deg[i] : 0;
    #pragma unroll
    for (int off = 1; off < 64; off <<= 1) v += __shfl_xor(v, off, 64);
    if ((tid & 63) == 0) ws[tid >> 6] = v;
    __syncthreads();
    if (tid == 0) bsum[b] = ws[0] + ws[1] + ws[2] + ws[3];
}

__global__ void k_scan_b(const int* __restrict__ bsum, int* __restrict__ boff) {
    __shared__ int wsum[4], wexc[4];
    int tid = threadIdx.x;
    int lane = tid & 63, wv = tid >> 6;
    int v = (tid < SCB) ? bsum[tid] : 0;
    int x = v;
    #pragma unroll
    for (int off = 1; off < 64; off <<= 1) {
        int y = __shfl_up(x, off, 64);
        if (lane >= off) x += y;
    }
    if (lane == 63) wsum[wv] = x;
    __syncthreads();
    if (tid == 0) { int run = 0; for (int w = 0; w < 4; w++) { wexc[w] = run; run += wsum[w]; } }
    __syncthreads();
    if (tid < SCB) boff[tid] = wexc[wv] + x - v;
}

__global__ void k_scan_c(const int* __restrict__ deg, const int* __restrict__ boff,
                         int* __restrict__ rp) {
    __shared__ int wsum[4], wexc[4];
    int b = blockIdx.x, tid = threadIdx.x;
    int i = b * 256 + tid;
    int v = (i < NN) ? deg[i] : 0;
    int lane = tid & 63, wv = tid >> 6;
    int x = v;
    #pragma unroll
    for (int off = 1; off < 64; off <<= 1) {
        int y = __shfl_up(x, off, 64);
        if (lane >= off) x += y;
    }
    if (lane == 63) wsum[wv] = x;
    __syncthreads();
    if (tid == 0) { int run = 0; for (int w = 0; w < 4; w++) { wexc[w] = run; run += wsum[w]; } }
    __syncthreads();
    if (i < NN) rp[i + 1] = boff[b] + wexc[wv] + x;
    if (b == 0 && tid == 0) rp[0] = 0;
}

__global__ void k_scatter(const int* src, const int* dst, const int* rp,
                          int* deg, int* cs) {
    int e = blockIdx.x * 256 + threadIdx.x;
    if (e < EE) {
        int d = dst[e];
        int pos = atomicSub(&deg[d], 1) - 1;
        cs[rp[d] + pos] = src[e];
    }
}

// Pack weights: fp16, transposed Bt[n][k], K padded.
__global__ void k_pack(const float* __restrict__ W_pool, const float* __restrict__ b_pool,
                       const float* __restrict__ W_app, const float* __restrict__ b_app,
                       const float* __restrict__ W_emb, const float* __restrict__ b_emb,
                       _Float16* Bt1, _Float16* Bt2, float* bb1,
                       _Float16* BtE, float* bbE) {
    int r = blockIdx.x * 256 + threadIdx.x;
    if (r < NL * 256 * 128) {
        int l = r / (256 * 128); int t = r % (256 * 128); int n = t / 128, k = t % 128;
        float v = 0.f;
        if (k < HID) {
            if (n < HID)                        v = W_pool[((size_t)l * HID + k) * HID + n];
            else if (n >= 128 && n < 128 + HID) v = W_app[((size_t)l * 216 + k) * HID + (n - 128)];
        }
        Bt1[r] = (_Float16)v; return;
    } r -= NL * 256 * 128;
    if (r < NL * 128 * 128) {
        int l = r / (128 * 128); int t = r % (128 * 128); int n = t / 128, k = t % 128;
        float v = (n < HID && k < HID) ? W_app[((size_t)l * 216 + 108 + k) * HID + n] : 0.f;
        Bt2[r] = (_Float16)v; return;
    } r -= NL * 128 * 128;
    if (r < NL * 256) {
        int l = r / 256, n = r % 256;
        float v = 0.f;
        if (n < HID) v = b_pool[l * HID + n];
        else if (n >= 128 && n < 128 + HID) v = b_app[l * HID + (n - 128)];
        bb1[r] = v; return;
    } r -= NL * 256;
    if (r < 128 * 32) {  // BtE[n][k]
        int n = r / 32, k = r % 32;
        BtE[r] = (n < HID) ? (_Float16)W_emb[k * HID + n] : (_Float16)0.f; return;
    } r -= 128 * 32;
    if (r < 128) { bbE[r] = (r < HID) ? b_emb[r] : 0.f; }
}

// embed via MFMA: h16[M,128] = feat(fp32->fp16)[M,32] @ BtE^T + bias; h = fp32 copy
__global__ __launch_bounds__(256)
void k_embed_mm(const float* __restrict__ feat, const _Float16* __restrict__ BtE,
                const float* __restrict__ bias,
                float* __restrict__ h, _Float16* __restrict__ h16) {
    __shared__ _Float16 Bl[128 * 32];
    int tid = threadIdx.x;
    for (int i = tid; i < 128 * 32 / 8; i += 256)
        ((uint4*)Bl)[i] = ((const uint4*)BtE)[i];
    __syncthreads();
    int lane = tid & 63, wid = tid >> 6, lm = lane & 15, lq = lane >> 4;
    int m0 = blockIdx.x * 64;
    floatx4 acc[4][2];
    #pragma unroll
    for (int mi = 0; mi < 4; mi++)
        #pragma unroll
        for (int ni = 0; ni < 2; ni++) { floatx4 z = {0.f,0.f,0.f,0.f}; acc[mi][ni] = z; }
    f16x8 a[4], b[2];
    #pragma unroll
    for (int mi = 0; mi < 4; mi++) {
        int row = m0 + mi * 16 + lm;
        f16x8 av;
        if (row < NN) {
            const float4 v0 = *(const float4*)(feat + (size_t)row * 32 + lq * 8);
            const float4 v1 = *(const float4*)(feat + (size_t)row * 32 + lq * 8 + 4);
            av[0] = (_Float16)v0.x; av[1] = (_Float16)v0.y;
            av[2] = (_Float16)v0.z; av[3] = (_Float16)v0.w;
            av[4] = (_Float16)v1.x; av[5] = (_Float16)v1.y;
            av[6] = (_Float16)v1.z; av[7] = (_Float16)v1.w;
        } else {
            #pragma unroll
            for (int j = 0; j < 8; j++) av[j] = (_Float16)0.f;
        }
        a[mi] = av;
    }
    #pragma unroll
    for (int ni = 0; ni < 2; ni++) {
        int col = wid * 32 + ni * 16 + lm;
        b[ni] = *(const f16x8*)&Bl[col * 32 + lq * 8];
    }
    #pragma unroll
    for (int mi = 0; mi < 4; mi++)
        #pragma unroll
        for (int ni = 0; ni < 2; ni++)
            acc[mi][ni] = __builtin_amdgcn_mfma_f32_16x16x32_f16(a[mi], b[ni], acc[mi][ni], 0, 0, 0);
    #pragma unroll
    for (int mi = 0; mi < 4; mi++)
        #pragma unroll
        for (int ni = 0; ni < 2; ni++) {
            int col = wid * 32 + ni * 16 + lm;
            float bc = bias[col];
            #pragma unroll
            for (int r = 0; r < 4; r++) {
                int row = m0 + mi * 16 + lq * 4 + r;
                if (row < NN) {
                    float v = acc[mi][ni][r] + bc;   // pad cols: Bt rows & bias are 0 -> v=0
                    h16[(size_t)row * 128 + col] = (_Float16)v;
                    if (col < HID) h[(size_t)row * HID + col] = v;
                }
            }
        }
}

// mm1: C[64,128] = A(h16)[64,128] @ Bt^T + bias. nt=0 -> hp16=relu fp16; nt=1 -> part fp32
__global__ __launch_bounds__(256)
void k_mm1(const _Float16* __restrict__ A, const _Float16* __restrict__ Bt,
           const float* __restrict__ bias,
           _Float16* __restrict__ hp16, float* __restrict__ part) {
    __shared__ _Float16 Bl[128 * LDSK];
    int tid = threadIdx.x;
    int nt = blockIdx.y;
    const _Float16* Bsrc = Bt + (size_t)nt * 128 * 128;
    for (int i = tid; i < 128 * 16; i += 256) {
        int rr = i >> 4, g = i & 15;
        *(uint4*)&Bl[rr * LDSK + g * 8] = *(const uint4*)(Bsrc + rr * 128 + g * 8);
    }
    __syncthreads();
    int lane = tid & 63, wid = tid >> 6, lm = lane & 15, lq = lane >> 4;
    int m0 = blockIdx.x * 64;
    floatx4 acc[4][2];
    #pragma unroll
    for (int mi = 0; mi < 4; mi++)
        #pragma unroll
        for (int ni = 0; ni < 2; ni++) { floatx4 z = {0.f,0.f,0.f,0.f}; acc[mi][ni] = z; }
    f16x8 zf = {(_Float16)0, (_Float16)0, (_Float16)0, (_Float16)0,
                (_Float16)0, (_Float16)0, (_Float16)0, (_Float16)0};
    #pragma unroll
    for (int ks = 0; ks < 4; ks++) {
        f16x8 a[4], b[2];
        #pragma unroll
        for (int mi = 0; mi < 4; mi++) {
            int row = m0 + mi * 16 + lm;
            a[mi] = (row < NN) ? *(const f16x8*)(A + (size_t)row * 128 + ks * 32 + lq * 8) : zf;
        }
        #pragma unroll
        for (int ni = 0; ni < 2; ni++)
            b[ni] = *(const f16x8*)&Bl[(wid * 32 + ni * 16 + lm) * LDSK + ks * 32 + lq * 8];
        #pragma unroll
        for (int mi = 0; mi < 4; mi++)
            #pragma unroll
            for (int ni = 0; ni < 2; ni++)
                acc[mi][ni] = __builtin_amdgcn_mfma_f32_16x16x32_f16(a[mi], b[ni], acc[mi][ni], 0, 0, 0);
    }
    #pragma unroll
    for (int mi = 0; mi < 4; mi++)
        #pragma unroll
        for (int ni = 0; ni < 2; ni++) {
            int col = wid * 32 + ni * 16 + lm;
            float bc = bias[nt * 128 + col];
            #pragma unroll
            for (int r = 0; r < 4; r++) {
                int row = m0 + mi * 16 + lq * 4 + r;
                if (row < NN) {
                    float v = acc[mi][ni][r] + bc;
                    if (nt == 0) hp16[(size_t)row * 128 + col] = (_Float16)fmaxf(v, 0.f);
                    else         part[(size_t)row * 128 + col] = v;
                }
            }
        }
}

// agg16[n][:] = fp16(mean over in-neighbors of hp16)
__global__ __launch_bounds__(128)
void k_agg(const _Float16* __restrict__ hp16, const int* __restrict__ rp,
           const int* __restrict__ cs, _Float16* __restrict__ agg16) {
    __shared__ float asl[8][128];
    int n = blockIdx.x, tid = threadIdx.x;
    int t = tid & 15, q = tid >> 4;
    int s0 = rp[n], s1 = rp[n + 1];
    float a[8];
    #pragma unroll
    for (int j = 0; j < 8; j++) a[j] = 0.f;
    int co = t * 8;
    for (int e = s0 + q; e < s1; e += 8) {
        f16x8 v = *(const f16x8*)(hp16 + (size_t)cs[e] * 128 + co);
        #pragma unroll
        for (int j = 0; j < 8; j++) a[j] += (float)v[j];
    }
    #pragma unroll
    for (int j = 0; j < 8; j++) asl[q][co + j] = a[j];
    __syncthreads();
    int col = tid;
    float s = 0.f;
    #pragma unroll
    for (int qq = 0; qq < 8; qq++) s += asl[qq][col];
    int dg = s1 - s0;
    float inv = 1.0f / (float)((dg > 1) ? dg : 1);
    agg16[(size_t)n * 128 + col] = (_Float16)(s * inv);
}

// mm2: bu = agg16 @ Bt2^T + part; l2norm -> relu -> h += ; write h fp32 + h16
__global__ __launch_bounds__(256)
void k_mm2(const _Float16* __restrict__ A, const _Float16* __restrict__ Bt,
           const float* __restrict__ part,
           float* __restrict__ h, _Float16* __restrict__ h16) {
    __shared__ _Float16 Bl[128 * LDSK];
    __shared__ float ssl[64 * 4];
    __shared__ float scl[64];
    int tid = threadIdx.x;
    for (int i = tid; i < 128 * 16; i += 256) {
        int rr = i >> 4, g = i & 15;
        *(uint4*)&Bl[rr * LDSK + g * 8] = *(const uint4*)(Bt + rr * 128 + g * 8);
    }
    __syncthreads();
    int lane = tid & 63, wid = tid >> 6, lm = lane & 15, lq = lane >> 4;
    int m0 = blockIdx.x * 64;
    floatx4 acc[4][2];
    #pragma unroll
    for (int mi = 0; mi < 4; mi++)
        #pragma unroll
        for (int ni = 0; ni < 2; ni++) { floatx4 z = {0.f,0.f,0.f,0.f}; acc[mi][ni] = z; }
    f16x8 zf = {(_Float16)0, (_Float16)0, (_Float16)0, (_Float16)0,
                (_Float16)0, (_Float16)0, (_Float16)0, (_Float16)0};
    #pragma unroll
    for (int ks = 0; ks < 4; ks++) {
        f16x8 a[4], b[2];
        #pragma unroll
        for (int mi = 0; mi < 4; mi++) {
            int row = m0 + mi * 16 + lm;
            a[mi] = (row < NN) ? *(const f16x8*)(A + (size_t)row * 128 + ks * 32 + lq * 8) : zf;
        }
        #pragma unroll
        for (int ni = 0; ni < 2; ni++)
            b[ni] = *(const f16x8*)&Bl[(wid * 32 + ni * 16 + lm) * LDSK + ks * 32 + lq * 8];
        #pragma unroll
        for (int mi = 0; mi < 4; mi++)
            #pragma unroll
            for (int ni = 0; ni < 2; ni++)
                acc[mi][ni] = __builtin_amdgcn_mfma_f32_16x16x32_f16(a[mi], b[ni], acc[mi][ni], 0, 0, 0);
    }
    #pragma unroll
    for (int mi = 0; mi < 4; mi++)
        #pragma unroll
        for (int ni = 0; ni < 2; ni++) {
            int col = wid * 32 + ni * 16 + lm;
            #pragma unroll
            for (int r = 0; r < 4; r++) {
                int row = m0 + mi * 16 + lq * 4 + r;
                acc[mi][ni][r] = (row < NN) ? acc[mi][ni][r] + part[(size_t)row * 128 + col] : 0.f;
            }
        }
    float ss[4][4];
    #pragma unroll
    for (int mi = 0; mi < 4; mi++)
        #pragma unroll
        for (int r = 0; r < 4; r++)
            ss[mi][r] = acc[mi][0][r] * acc[mi][0][r] + acc[mi][1][r] * acc[mi][1][r];
    #pragma unroll
    for (int off = 1; off < 16; off <<= 1)
        #pragma unroll
        for (int mi = 0; mi < 4; mi++)
            #pragma unroll
            for (int r = 0; r < 4; r++)
                ss[mi][r] += __shfl_xor(ss[mi][r], off, 64);
    if (lm == 0) {
        #pragma unroll
        for (int mi = 0; mi < 4; mi++)
            #pragma unroll
            for (int r = 0; r < 4; r++)
                ssl[(mi * 16 + lq * 4 + r) * 4 + wid] = ss[mi][r];
    }
    __syncthreads();
    if (tid < 64) {
        float s = ssl[tid * 4] + ssl[tid * 4 + 1] + ssl[tid * 4 + 2] + ssl[tid * 4 + 3];
        scl[tid] = 1.0f / fmaxf(sqrtf(s), 1e-12f);
    }
    __syncthreads();
    #pragma unroll
    for (int mi = 0; mi < 4; mi++)
        #pragma unroll
        for (int ni = 0; ni < 2; ni++) {
            int col = wid * 32 + ni * 16 + lm;
            if (col < HID) {
                #pragma unroll
                for (int r = 0; r < 4; r++) {
                    int rl = mi * 16 + lq * 4 + r;
                    int row = m0 + rl;
                    if (row < NN) {
                        float v = fmaxf(acc[mi][ni][r] * scl[rl], 0.f);
                        float hn = h[(size_t)row * HID + col] + v;
                        h[(size_t)row * HID + col] = hn;
                        h16[(size_t)row * 128 + col] = (_Float16)hn;
                    }
                }
            }
        }
}

// readout phase 1: per-(graph, slice) partial column sums of h
__global__ __launch_bounds__(128)
void k_seg(const float* __restrict__ h, const int* __restrict__ gid,
           float* __restrict__ hgp) {
    __shared__ int se[2];
    int g = blockIdx.x, sl = blockIdx.y, tid = threadIdx.x;
    if (tid < 2) {
        int key = g + tid, lo = 0, hi = NN;
        while (lo < hi) {
            int mid = (lo + hi) >> 1;
            if (gid[mid] < key) lo = mid + 1; else hi = mid;
        }
        se[tid] = lo;
    }
    __syncthreads();
    int s = se[0], e = se[1];
    int cnt = e - s;
    int chunk = (cnt + RS - 1) / RS;
    int ls = s + sl * chunk;
    int le = min(e, ls + chunk);
    if (tid < HID) {
        float acc = 0.f;
        for (int n = ls; n < le; n++) acc += h[(size_t)n * HID + tid];
        hgp[((size_t)g * RS + sl) * HID + tid] = acc;
    }
}

// readout phase 2: combine partials, mean, 3-layer MLP
__global__ __launch_bounds__(128)
void k_mlp(const float* __restrict__ hgp, const int* __restrict__ gid,
           const float* __restrict__ W1, const float* __restrict__ b1,
           const float* __restrict__ W2, const float* __restrict__ b2,
           const float* __restrict__ W3, const float* __restrict__ b3,
           float* __restrict__ out) {
    __shared__ float hg[HID];
    __shared__ float y1[54];
    __shared__ float y2[27];
    __shared__ int se[2];
    int g = blockIdx.x, tid = threadIdx.x;
    if (tid < 2) {
        int key = g + tid, lo = 0, hi = NN;
        while (lo < hi) {
            int mid = (lo + hi) >> 1;
            if (gid[mid] < key) lo = mid + 1; else hi = mid;
        }
        se[tid] = lo;
    }
    __syncthreads();
    int cnt = se[1] - se[0];
    if (tid < HID) {
        float acc = 0.f;
        #pragma unroll
        for (int sl = 0; sl < RS; sl++) acc += hgp[((size_t)g * RS + sl) * HID + tid];
        hg[tid] = acc / (float)((cnt > 1) ? cnt : 1);
    }
    __syncthreads();
    if (tid < 54) {
        float a = b1[tid];
        for (int k = 0; k < HID; k++) a += hg[k] * W1[k * 54 + tid];
        y1[tid] = fmaxf(a, 0.f);
    }
    __syncthreads();
    if (tid < 27) {
        float a = b2[tid];
        for (int k = 0; k < 54; k++) a += y1[k] * W2[k * 27 + tid];
        y2[tid] = fmaxf(a, 0.f);
    }
    __syncthreads();
    if (tid < 10) {
        float a = b3[tid];
        for (int k = 0; k < 27; k++) a += y2[k] * W3[k * 10 + tid];
        out[g * 10 + tid] = a;
    }
}

extern "C" void kernel_launch(void* const* d_in, const int* in_sizes, int n_in,
                              void* d_out, int out_size, void* d_ws, size_t ws_size,
                              hipStream_t stream) {
    float* out = (float*)d_out;
    (void)in_sizes; (void)n_in; (void)ws_size; (void)out_size;

    const float* feat   = (const float*)d_in[0];
    const int*   src    = (const int*)d_in[4];
    const int*   dst    = (const int*)d_in[5];
    const int*   gid    = (const int*)d_in[6];
    const float* W_emb  = (const float*)d_in[7];
    const float* b_emb  = (const float*)d_in[8];
    const float* W_pool = (const float*)d_in[9];
    const float* b_pool = (const float*)d_in[10];
    const float* W_app  = (const float*)d_in[11];
    const float* b_app  = (const float*)d_in[12];
    const float* W1     = (const float*)d_in[13];
    const float* b1     = (const float*)d_in[14];
    const float* W2     = (const float*)d_in[15];
    const float* b2     = (const float*)d_in[16];
    const float* W3     = (const float*)d_in[17];
    const float* b3     = (const float*)d_in[18];

    char* ws = (char*)d_ws;
    size_t off = 0;
    auto take = [&](size_t bytes) { char* p = ws + off; off += (bytes + 255) & ~(size_t)255; return p; };
    float*     h     = (float*)take((size_t)NN * HID * 4);
    _Float16*  h16   = (_Float16*)take((size_t)NN * 128 * 2);
    _Float16*  hp16  = (_Float16*)take((size_t)NN * 128 * 2);
    _Float16*  agg16 = (_Float16*)take((size_t)NN * 128 * 2);
    float*     part  = (float*)take((size_t)NN * 128 * 4);
    int*       cs    = (int*)take((size_t)EE * 4);
    int*       deg   = (int*)take((size_t)NN * 4);
    int*       rp    = (int*)take((size_t)(NN + 1) * 4);
    int*       bsum  = (int*)take((size_t)SCB * 4);
    int*       boff  = (int*)take((size_t)SCB * 4);
    float*     hgp   = (float*)take((size_t)GG * RS * HID * 4);
    _Float16*  Bt1   = (_Float16*)take((size_t)NL * 256 * 128 * 2);
    _Float16*  Bt2   = (_Float16*)take((size_t)NL * 128 * 128 * 2);
    float*     bb1   = (float*)take((size_t)NL * 256 * 4);
    _Float16*  BtE   = (_Float16*)take((size_t)128 * 32 * 2);
    float*     bbE   = (float*)take((size_t)128 * 4);

    hipLaunchKernelGGL(k_zero, dim3((NN + 255) / 256), dim3(256), 0, stream, deg);
    hipLaunchKernelGGL(k_hist, dim3((EE + 255) / 256), dim3(256), 0, stream, dst, deg);
    hipLaunchKernelGGL(k_scan_a, dim3(SCB), dim3(256), 0, stream, deg, bsum);
    hipLaunchKernelGGL(k_scan_b, dim3(1), dim3(256), 0, stream, bsum, boff);
    hipLaunchKernelGGL(k_scan_c, dim3(SCB), dim3(256), 0, stream, deg, boff, rp);
    hipLaunchKernelGGL(k_scatter, dim3((EE + 255) / 256), dim3(256), 0, stream,
                       src, dst, rp, deg, cs);

    const int PACK_TOTAL = NL * 256 * 128 + NL * 128 * 128 + NL * 256 + 128 * 32 + 128;
    hipLaunchKernelGGL(k_pack, dim3((PACK_TOTAL + 255) / 256), dim3(256), 0, stream,
                       W_pool, b_pool, W_app, b_app, W_emb, b_emb,
                       Bt1, Bt2, bb1, BtE, bbE);

    hipLaunchKernelGGL(k_embed_mm, dim3(MB), dim3(256), 0, stream,
                       feat, BtE, bbE, h, h16);

    for (int l = 0; l < NL; l++) {
        hipLaunchKernelGGL(k_mm1, dim3(MB, 2), dim3(256), 0, stream,
                           h16, Bt1 + (size_t)l * 256 * 128, bb1 + (size_t)l * 256,
                           hp16, part);
        hipLaunchKernelGGL(k_agg, dim3(NN), dim3(128), 0, stream, hp16, rp, cs, agg16);
        hipLaunchKernelGGL(k_mm2, dim3(MB), dim3(256), 0, stream,
                           agg16, Bt2 + (size_t)l * 128 * 128, part, h, h16);
    }
    hipLaunchKernelGGL(k_seg, dim3(GG, RS), dim3(128), 0, stream, h, gid, hgp);
    hipLaunchKernelGGL(k_mlp, dim3(GG), dim3(128), 0, stream,
                       hgp, gid, W1, b1, W2, b2, W3, b3, out);
}

// Round 20
// 597.076 us; speedup vs baseline: 1.2851x; 1.0229x over previous
//
#include <hip/hip_runtime.h>

#define NN 50000
#define EE 800000
#define GG 256
#define IND 32
#define HID 108
#define NL 4
#define MB 782            // ceil(50000/64) M-tiles
#define LDSK 136          // LDS B row stride (halves) for 128-wide K (272B = 17*16)
#define LDSK2 264         // LDS B row stride (halves) for 256-wide K (528B = 33*16)
#define SCB 196           // ceil(50000/256) scan tiles
#define RS 8              // readout slices per graph

typedef __attribute__((ext_vector_type(8))) _Float16 f16x8;
typedef __attribute__((ext_vector_type(4))) float floatx4;

__global__ void k_zero(int* deg) {
    int i = blockIdx.x * 256 + threadIdx.x;
    if (i < NN) deg[i] = 0;
}

__global__ void k_hist(const int* dst, int* deg) {
    int e = blockIdx.x * 256 + threadIdx.x;
    if (e < EE) atomicAdd(&deg[dst[e]], 1);
}

// ---- 3-phase coalesced scan ----
__global__ void k_scan_a(const int* __restrict__ deg, int* __restrict__ bsum) {
    __shared__ int ws[4];
    int b = blockIdx.x, tid = threadIdx.x;
    int i = b * 256 + tid;
    int v = (i < NN) ? deg[i] : 0;
    #pragma unroll
    for (int off = 1; off < 64; off <<= 1) v += __shfl_xor(v, off, 64);
    if ((tid & 63) == 0) ws[tid >> 6] = v;
    __syncthreads();
    if (tid == 0) bsum[b] = ws[0] + ws[1] + ws[2] + ws[3];
}

__global__ void k_scan_b(const int* __restrict__ bsum, int* __restrict__ boff) {
    __shared__ int wsum[4], wexc[4];
    int tid = threadIdx.x;
    int lane = tid & 63, wv = tid >> 6;
    int v = (tid < SCB) ? bsum[tid] : 0;
    int x = v;
    #pragma unroll
    for (int off = 1; off < 64; off <<= 1) {
        int y = __shfl_up(x, off, 64);
        if (lane >= off) x += y;
    }
    if (lane == 63) wsum[wv] = x;
    __syncthreads();
    if (tid == 0) { int run = 0; for (int w = 0; w < 4; w++) { wexc[w] = run; run += wsum[w]; } }
    __syncthreads();
    if (tid < SCB) boff[tid] = wexc[wv] + x - v;
}

__global__ void k_scan_c(const int* __restrict__ deg, const int* __restrict__ boff,
                         int* __restrict__ rp) {
    __shared__ int wsum[4], wexc[4];
    int b = blockIdx.x, tid = threadIdx.x;
    int i = b * 256 + tid;
    int v = (i < NN) ? deg[i] : 0;
    int lane = tid & 63, wv = tid >> 6;
    int x = v;
    #pragma unroll
    for (int off = 1; off < 64; off <<= 1) {
        int y = __shfl_up(x, off, 64);
        if (lane >= off) x += y;
    }
    if (lane == 63) wsum[wv] = x;
    __syncthreads();
    if (tid == 0) { int run = 0; for (int w = 0; w < 4; w++) { wexc[w] = run; run += wsum[w]; } }
    __syncthreads();
    if (i < NN) rp[i + 1] = boff[b] + wexc[wv] + x;
    if (b == 0 && tid == 0) rp[0] = 0;
}

__global__ void k_scatter(const int* src, const int* dst, const int* rp,
                          int* deg, int* cs) {
    int e = blockIdx.x * 256 + threadIdx.x;
    if (e < EE) {
        int d = dst[e];
        int pos = atomicSub(&deg[d], 1) - 1;
        cs[rp[d] + pos] = src[e];
    }
}

// Pack weights (fp16, transposed, padded):
// Bt1[l][128][128]  : pool, n<108,k<108 -> W_pool[l][k][n]
// BtA[l][108][256]  : app,  row n<108; k<108 -> W_app[l][k][n]; 128<=k<236 -> W_app[l][108+k-128][n]
// bbP[l][128], bbA[l][128], BtE[128][32], bbE[128]
__global__ void k_pack(const float* __restrict__ W_pool, const float* __restrict__ b_pool,
                       const float* __restrict__ W_app, const float* __restrict__ b_app,
                       const float* __restrict__ W_emb, const float* __restrict__ b_emb,
                       _Float16* Bt1, _Float16* BtA, float* bbP, float* bbA,
                       _Float16* BtE, float* bbE) {
    int r = blockIdx.x * 256 + threadIdx.x;
    if (r < NL * 128 * 128) {
        int l = r / (128 * 128); int t = r % (128 * 128); int n = t / 128, k = t % 128;
        float v = (n < HID && k < HID) ? W_pool[((size_t)l * HID + k) * HID + n] : 0.f;
        Bt1[r] = (_Float16)v; return;
    } r -= NL * 128 * 128;
    if (r < NL * 108 * 256) {
        int l = r / (108 * 256); int t = r % (108 * 256); int n = t / 256, k = t % 256;
        float v = 0.f;
        if (k < HID)                        v = W_app[((size_t)l * 216 + k) * HID + n];
        else if (k >= 128 && k < 128 + HID) v = W_app[((size_t)l * 216 + 108 + (k - 128)) * HID + n];
        BtA[r] = (_Float16)v; return;
    } r -= NL * 108 * 256;
    if (r < NL * 128) { int l = r / 128, n = r % 128; bbP[r] = (n < HID) ? b_pool[l * HID + n] : 0.f; return; } r -= NL * 128;
    if (r < NL * 128) { int l = r / 128, n = r % 128; bbA[r] = (n < HID) ? b_app[l * HID + n] : 0.f; return; } r -= NL * 128;
    if (r < 128 * 32) {
        int n = r / 32, k = r % 32;
        BtE[r] = (n < HID) ? (_Float16)W_emb[k * HID + n] : (_Float16)0.f; return;
    } r -= 128 * 32;
    if (r < 128) { bbE[r] = (r < HID) ? b_emb[r] : 0.f; }
}

// embed via MFMA: h16[M,128] = feat(fp32->fp16)[M,32] @ BtE^T + bias; h = fp32 copy
__global__ __launch_bounds__(256)
void k_embed_mm(const float* __restrict__ feat, const _Float16* __restrict__ BtE,
                const float* __restrict__ bias,
                float* __restrict__ h, _Float16* __restrict__ h16) {
    __shared__ _Float16 Bl[128 * 32];
    int tid = threadIdx.x;
    for (int i = tid; i < 128 * 32 / 8; i += 256)
        ((uint4*)Bl)[i] = ((const uint4*)BtE)[i];
    __syncthreads();
    int lane = tid & 63, wid = tid >> 6, lm = lane & 15, lq = lane >> 4;
    int m0 = blockIdx.x * 64;
    floatx4 acc[4][2];
    #pragma unroll
    for (int mi = 0; mi < 4; mi++)
        #pragma unroll
        for (int ni = 0; ni < 2; ni++) { floatx4 z = {0.f,0.f,0.f,0.f}; acc[mi][ni] = z; }
    f16x8 a[4], b[2];
    #pragma unroll
    for (int mi = 0; mi < 4; mi++) {
        int row = m0 + mi * 16 + lm;
        f16x8 av;
        if (row < NN) {
            const float4 v0 = *(const float4*)(feat + (size_t)row * 32 + lq * 8);
            const float4 v1 = *(const float4*)(feat + (size_t)row * 32 + lq * 8 + 4);
            av[0] = (_Float16)v0.x; av[1] = (_Float16)v0.y;
            av[2] = (_Float16)v0.z; av[3] = (_Float16)v0.w;
            av[4] = (_Float16)v1.x; av[5] = (_Float16)v1.y;
            av[6] = (_Float16)v1.z; av[7] = (_Float16)v1.w;
        } else {
            #pragma unroll
            for (int j = 0; j < 8; j++) av[j] = (_Float16)0.f;
        }
        a[mi] = av;
    }
    #pragma unroll
    for (int ni = 0; ni < 2; ni++) {
        int col = wid * 32 + ni * 16 + lm;
        b[ni] = *(const f16x8*)&Bl[col * 32 + lq * 8];
    }
    #pragma unroll
    for (int mi = 0; mi < 4; mi++)
        #pragma unroll
        for (int ni = 0; ni < 2; ni++)
            acc[mi][ni] = __builtin_amdgcn_mfma_f32_16x16x32_f16(a[mi], b[ni], acc[mi][ni], 0, 0, 0);
    #pragma unroll
    for (int mi = 0; mi < 4; mi++)
        #pragma unroll
        for (int ni = 0; ni < 2; ni++) {
            int col = wid * 32 + ni * 16 + lm;
            float bc = bias[col];
            #pragma unroll
            for (int r = 0; r < 4; r++) {
                int row = m0 + mi * 16 + lq * 4 + r;
                if (row < NN) {
                    float v = acc[mi][ni][r] + bc;
                    h16[(size_t)row * 128 + col] = (_Float16)v;
                    if (col < HID) h[(size_t)row * HID + col] = v;
                }
            }
        }
}

// mm1 (pool only): hp16 = fp16(relu(h16 @ Bt1^T + bias))
__global__ __launch_bounds__(256)
void k_mm1(const _Float16* __restrict__ A, const _Float16* __restrict__ Bt,
           const float* __restrict__ bias, _Float16* __restrict__ hp16) {
    __shared__ _Float16 Bl[128 * LDSK];
    int tid = threadIdx.x;
    for (int i = tid; i < 128 * 16; i += 256) {
        int rr = i >> 4, g = i & 15;
        *(uint4*)&Bl[rr * LDSK + g * 8] = *(const uint4*)(Bt + rr * 128 + g * 8);
    }
    __syncthreads();
    int lane = tid & 63, wid = tid >> 6, lm = lane & 15, lq = lane >> 4;
    int m0 = blockIdx.x * 64;
    floatx4 acc[4][2];
    #pragma unroll
    for (int mi = 0; mi < 4; mi++)
        #pragma unroll
        for (int ni = 0; ni < 2; ni++) { floatx4 z = {0.f,0.f,0.f,0.f}; acc[mi][ni] = z; }
    f16x8 zf = {(_Float16)0, (_Float16)0, (_Float16)0, (_Float16)0,
                (_Float16)0, (_Float16)0, (_Float16)0, (_Float16)0};
    #pragma unroll
    for (int ks = 0; ks < 4; ks++) {
        f16x8 a[4], b[2];
        #pragma unroll
        for (int mi = 0; mi < 4; mi++) {
            int row = m0 + mi * 16 + lm;
            a[mi] = (row < NN) ? *(const f16x8*)(A + (size_t)row * 128 + ks * 32 + lq * 8) : zf;
        }
        #pragma unroll
        for (int ni = 0; ni < 2; ni++)
            b[ni] = *(const f16x8*)&Bl[(wid * 32 + ni * 16 + lm) * LDSK + ks * 32 + lq * 8];
        #pragma unroll
        for (int mi = 0; mi < 4; mi++)
            #pragma unroll
            for (int ni = 0; ni < 2; ni++)
                acc[mi][ni] = __builtin_amdgcn_mfma_f32_16x16x32_f16(a[mi], b[ni], acc[mi][ni], 0, 0, 0);
    }
    #pragma unroll
    for (int mi = 0; mi < 4; mi++)
        #pragma unroll
        for (int ni = 0; ni < 2; ni++) {
            int col = wid * 32 + ni * 16 + lm;
            float bc = bias[col];
            #pragma unroll
            for (int r = 0; r < 4; r++) {
                int row = m0 + mi * 16 + lq * 4 + r;
                if (row < NN)
                    hp16[(size_t)row * 128 + col] = (_Float16)fmaxf(acc[mi][ni][r] + bc, 0.f);
            }
        }
}

// agg16[n][:] = fp16(mean over in-neighbors of hp16)
__global__ __launch_bounds__(128)
void k_agg(const _Float16* __restrict__ hp16, const int* __restrict__ rp,
           const int* __restrict__ cs, _Float16* __restrict__ agg16) {
    __shared__ float asl[8][128];
    int n = blockIdx.x, tid = threadIdx.x;
    int t = tid & 15, q = tid >> 4;
    int s0 = rp[n], s1 = rp[n + 1];
    float a[8];
    #pragma unroll
    for (int j = 0; j < 8; j++) a[j] = 0.f;
    int co = t * 8;
    for (int e = s0 + q; e < s1; e += 8) {
        f16x8 v = *(const f16x8*)(hp16 + (size_t)cs[e] * 128 + co);
        #pragma unroll
        for (int j = 0; j < 8; j++) a[j] += (float)v[j];
    }
    #pragma unroll
    for (int j = 0; j < 8; j++) asl[q][co + j] = a[j];
    __syncthreads();
    int col = tid;
    float s = 0.f;
    #pragma unroll
    for (int qq = 0; qq < 8; qq++) s += asl[qq][col];
    int dg = s1 - s0;
    float inv = 1.0f / (float)((dg > 1) ? dg : 1);
    agg16[(size_t)n * 128 + col] = (_Float16)(s * inv);
}

// app (fused K=256): bu = [h16|agg16] @ BtA^T + bias; l2norm -> relu -> h += ;
// write h fp32 + h16. B-tile: rows 0..107 staged (57KB); cols>=108 masked.
__global__ __launch_bounds__(256)
void k_app_mm(const _Float16* __restrict__ Ah, const _Float16* __restrict__ Ag,
              const _Float16* __restrict__ Bt, const float* __restrict__ bias,
              float* __restrict__ h, _Float16* __restrict__ h16) {
    __shared__ _Float16 Bl[108 * LDSK2];
    __shared__ float ssl[64 * 4];
    __shared__ float scl[64];
    int tid = threadIdx.x;
    for (int i = tid; i < 108 * 32; i += 256) {   // 108 rows x 32 uint4
        int rr = i >> 5, g = i & 31;
        *(uint4*)&Bl[rr * LDSK2 + g * 8] = ((const uint4*)Bt)[i];
    }
    __syncthreads();
    int lane = tid & 63, wid = tid >> 6, lm = lane & 15, lq = lane >> 4;
    int m0 = blockIdx.x * 64;
    floatx4 acc[4][2];
    #pragma unroll
    for (int mi = 0; mi < 4; mi++)
        #pragma unroll
        for (int ni = 0; ni < 2; ni++) { floatx4 z = {0.f,0.f,0.f,0.f}; acc[mi][ni] = z; }
    f16x8 zf = {(_Float16)0, (_Float16)0, (_Float16)0, (_Float16)0,
                (_Float16)0, (_Float16)0, (_Float16)0, (_Float16)0};
    int colc[2];
    #pragma unroll
    for (int ni = 0; ni < 2; ni++) {
        int col = wid * 32 + ni * 16 + lm;
        colc[ni] = (col < HID) ? col : 0;   // clamp LDS row for masked cols
    }
    #pragma unroll
    for (int ks = 0; ks < 8; ks++) {
        const _Float16* Asrc = (ks < 4) ? Ah : Ag;
        int ko = (ks & 3) * 32 + lq * 8;
        f16x8 a[4], b[2];
        #pragma unroll
        for (int mi = 0; mi < 4; mi++) {
            int row = m0 + mi * 16 + lm;
            a[mi] = (row < NN) ? *(const f16x8*)(Asrc + (size_t)row * 128 + ko) : zf;
        }
        #pragma unroll
        for (int ni = 0; ni < 2; ni++)
            b[ni] = *(const f16x8*)&Bl[colc[ni] * LDSK2 + ks * 32 + lq * 8];
        #pragma unroll
        for (int mi = 0; mi < 4; mi++)
            #pragma unroll
            for (int ni = 0; ni < 2; ni++)
                acc[mi][ni] = __builtin_amdgcn_mfma_f32_16x16x32_f16(a[mi], b[ni], acc[mi][ni], 0, 0, 0);
    }
    // bias + masked sum of squares
    int cval[2];
    #pragma unroll
    for (int ni = 0; ni < 2; ni++) {
        int col = wid * 32 + ni * 16 + lm;
        cval[ni] = (col < HID);
        float bc = bias[col];
        #pragma unroll
        for (int r = 0; r < 4; r++) acc[0][ni][r] += 0.f;  // keep structure simple
        #pragma unroll
        for (int mi = 0; mi < 4; mi++)
            #pragma unroll
            for (int r = 0; r < 4; r++) acc[mi][ni][r] += bc;
    }
    float ss[4][4];
    #pragma unroll
    for (int mi = 0; mi < 4; mi++)
        #pragma unroll
        for (int r = 0; r < 4; r++) {
            float c0 = cval[0] ? acc[mi][0][r] : 0.f;
            float c1 = cval[1] ? acc[mi][1][r] : 0.f;
            ss[mi][r] = c0 * c0 + c1 * c1;
        }
    #pragma unroll
    for (int off = 1; off < 16; off <<= 1)
        #pragma unroll
        for (int mi = 0; mi < 4; mi++)
            #pragma unroll
            for (int r = 0; r < 4; r++)
                ss[mi][r] += __shfl_xor(ss[mi][r], off, 64);
    if (lm == 0) {
        #pragma unroll
        for (int mi = 0; mi < 4; mi++)
            #pragma unroll
            for (int r = 0; r < 4; r++)
                ssl[(mi * 16 + lq * 4 + r) * 4 + wid] = ss[mi][r];
    }
    __syncthreads();
    if (tid < 64) {
        float s = ssl[tid * 4] + ssl[tid * 4 + 1] + ssl[tid * 4 + 2] + ssl[tid * 4 + 3];
        scl[tid] = 1.0f / fmaxf(sqrtf(s), 1e-12f);
    }
    __syncthreads();
    #pragma unroll
    for (int mi = 0; mi < 4; mi++)
        #pragma unroll
        for (int ni = 0; ni < 2; ni++) {
            int col = wid * 32 + ni * 16 + lm;
            if (col < HID) {
                #pragma unroll
                for (int r = 0; r < 4; r++) {
                    int rl = mi * 16 + lq * 4 + r;
                    int row = m0 + rl;
                    if (row < NN) {
                        float v = fmaxf(acc[mi][ni][r] * scl[rl], 0.f);
                        float hn = h[(size_t)row * HID + col] + v;
                        h[(size_t)row * HID + col] = hn;
                        h16[(size_t)row * 128 + col] = (_Float16)hn;
                    }
                }
            }
        }
}

// readout phase 1: per-(graph, slice) partial column sums of h
__global__ __launch_bounds__(128)
void k_seg(const float* __restrict__ h, const int* __restrict__ gid,
           float* __restrict__ hgp) {
    __shared__ int se[2];
    int g = blockIdx.x, sl = blockIdx.y, tid = threadIdx.x;
    if (tid < 2) {
        int key = g + tid, lo = 0, hi = NN;
        while (lo < hi) {
            int mid = (lo + hi) >> 1;
            if (gid[mid] < key) lo = mid + 1; else hi = mid;
        }
        se[tid] = lo;
    }
    __syncthreads();
    int s = se[0], e = se[1];
    int cnt = e - s;
    int chunk = (cnt + RS - 1) / RS;
    int ls = s + sl * chunk;
    int le = min(e, ls + chunk);
    if (tid < HID) {
        float acc = 0.f;
        for (int n = ls; n < le; n++) acc += h[(size_t)n * HID + tid];
        hgp[((size_t)g * RS + sl) * HID + tid] = acc;
    }
}

// readout phase 2: combine partials, mean, 3-layer MLP
__global__ __launch_bounds__(128)
void k_mlp(const float* __restrict__ hgp, const int* __restrict__ gid,
           const float* __restrict__ W1, const float* __restrict__ b1,
           const float* __restrict__ W2, const float* __restrict__ b2,
           const float* __restrict__ W3, const float* __restrict__ b3,
           float* __restrict__ out) {
    __shared__ float hg[HID];
    __shared__ float y1[54];
    __shared__ float y2[27];
    __shared__ int se[2];
    int g = blockIdx.x, tid = threadIdx.x;
    if (tid < 2) {
        int key = g + tid, lo = 0, hi = NN;
        while (lo < hi) {
            int mid = (lo + hi) >> 1;
            if (gid[mid] < key) lo = mid + 1; else hi = mid;
        }
        se[tid] = lo;
    }
    __syncthreads();
    int cnt = se[1] - se[0];
    if (tid < HID) {
        float acc = 0.f;
        #pragma unroll
        for (int sl = 0; sl < RS; sl++) acc += hgp[((size_t)g * RS + sl) * HID + tid];
        hg[tid] = acc / (float)((cnt > 1) ? cnt : 1);
    }
    __syncthreads();
    if (tid < 54) {
        float a = b1[tid];
        for (int k = 0; k < HID; k++) a += hg[k] * W1[k * 54 + tid];
        y1[tid] = fmaxf(a, 0.f);
    }
    __syncthreads();
    if (tid < 27) {
        float a = b2[tid];
        for (int k = 0; k < 54; k++) a += y1[k] * W2[k * 27 + tid];
        y2[tid] = fmaxf(a, 0.f);
    }
    __syncthreads();
    if (tid < 10) {
        float a = b3[tid];
        for (int k = 0; k < 27; k++) a += y2[k] * W3[k * 10 + tid];
        out[g * 10 + tid] = a;
    }
}

extern "C" void kernel_launch(void* const* d_in, const int* in_sizes, int n_in,
                              void* d_out, int out_size, void* d_ws, size_t ws_size,
                              hipStream_t stream) {
    float* out = (float*)d_out;
    (void)in_sizes; (void)n_in; (void)ws_size; (void)out_size;

    const float* feat   = (const float*)d_in[0];
    const int*   src    = (const int*)d_in[4];
    const int*   dst    = (const int*)d_in[5];
    const int*   gid    = (const int*)d_in[6];
    const float* W_emb  = (const float*)d_in[7];
    const float* b_emb  = (const float*)d_in[8];
    const float* W_pool = (const float*)d_in[9];
    const float* b_pool = (const float*)d_in[10];
    const float* W_app  = (const float*)d_in[11];
    const float* b_app  = (const float*)d_in[12];
    const float* W1     = (const float*)d_in[13];
    const float* b1     = (const float*)d_in[14];
    const float* W2     = (const float*)d_in[15];
    const float* b2     = (const float*)d_in[16];
    const float* W3     = (const float*)d_in[17];
    const float* b3     = (const float*)d_in[18];

    char* ws = (char*)d_ws;
    size_t off = 0;
    auto take = [&](size_t bytes) { char* p = ws + off; off += (bytes + 255) & ~(size_t)255; return p; };
    float*     h     = (float*)take((size_t)NN * HID * 4);
    _Float16*  h16   = (_Float16*)take((size_t)NN * 128 * 2);
    _Float16*  hp16  = (_Float16*)take((size_t)NN * 128 * 2);
    _Float16*  agg16 = (_Float16*)take((size_t)NN * 128 * 2);
    int*       cs    = (int*)take((size_t)EE * 4);
    int*       deg   = (int*)take((size_t)NN * 4);
    int*       rp    = (int*)take((size_t)(NN + 1) * 4);
    int*       bsum  = (int*)take((size_t)SCB * 4);
    int*       boff  = (int*)take((size_t)SCB * 4);
    float*     hgp   = (float*)take((size_t)GG * RS * HID * 4);
    _Float16*  Bt1   = (_Float16*)take((size_t)NL * 128 * 128 * 2);
    _Float16*  BtA   = (_Float16*)take((size_t)NL * 108 * 256 * 2);
    float*     bbP   = (float*)take((size_t)NL * 128 * 4);
    float*     bbA   = (float*)take((size_t)NL * 128 * 4);
    _Float16*  BtE   = (_Float16*)take((size_t)128 * 32 * 2);
    float*     bbE   = (float*)take((size_t)128 * 4);

    hipLaunchKernelGGL(k_zero, dim3((NN + 255) / 256), dim3(256), 0, stream, deg);
    hipLaunchKernelGGL(k_hist, dim3((EE + 255) / 256), dim3(256), 0, stream, dst, deg);
    hipLaunchKernelGGL(k_scan_a, dim3(SCB), dim3(256), 0, stream, deg, bsum);
    hipLaunchKernelGGL(k_scan_b, dim3(1), dim3(256), 0, stream, bsum, boff);
    hipLaunchKernelGGL(k_scan_c, dim3(SCB), dim3(256), 0, stream, deg, boff, rp);
    hipLaunchKernelGGL(k_scatter, dim3((EE + 255) / 256), dim3(256), 0, stream,
                       src, dst, rp, deg, cs);

    const int PACK_TOTAL = NL * 128 * 128 + NL * 108 * 256 + NL * 128 + NL * 128 + 128 * 32 + 128;
    hipLaunchKernelGGL(k_pack, dim3((PACK_TOTAL + 255) / 256), dim3(256), 0, stream,
                       W_pool, b_pool, W_app, b_app, W_emb, b_emb,
                       Bt1, BtA, bbP, bbA, BtE, bbE);

    hipLaunchKernelGGL(k_embed_mm, dim3(MB), dim3(256), 0, stream,
                       feat, BtE, bbE, h, h16);

    for (int l = 0; l < NL; l++) {
        hipLaunchKernelGGL(k_mm1, dim3(MB), dim3(256), 0, stream,
                           h16, Bt1 + (size_t)l * 128 * 128, bbP + (size_t)l * 128, hp16);
        hipLaunchKernelGGL(k_agg, dim3(NN), dim3(128), 0, stream, hp16, rp, cs, agg16);
        hipLaunchKernelGGL(k_app_mm, dim3(MB), dim3(256), 0, stream,
                           h16, agg16, BtA + (size_t)l * 108 * 256, bbA + (size_t)l * 128,
                           h, h16);
    }
    hipLaunchKernelGGL(k_seg, dim3(GG, RS), dim3(128), 0, stream, h, gid, hgp);
    hipLaunchKernelGGL(k_mlp, dim3(GG), dim3(128), 0, stream,
                       hgp, gid, W1, b1, W2, b2, W3, b3, out);
}

// Round 21
// 560.965 us; speedup vs baseline: 1.3678x; 1.0644x over previous
//
#include <hip/hip_runtime.h>

#define NN 50000
#define EE 800000
#define GG 256
#define IND 32
#define HID 108
#define NL 4
#define MB 782            // ceil(50000/64) M-tiles
#define LDSK 136          // LDS B row stride (halves) for 128-wide K (272B = 17*16)
#define SCB 196           // ceil(50000/256) scan tiles
#define RS 8              // readout slices per graph

typedef __attribute__((ext_vector_type(8))) _Float16 f16x8;
typedef __attribute__((ext_vector_type(4))) float floatx4;

__global__ void k_zero(int* deg) {
    int i = blockIdx.x * 256 + threadIdx.x;
    if (i < NN) deg[i] = 0;
}

__global__ void k_hist(const int* dst, int* deg) {
    int e = blockIdx.x * 256 + threadIdx.x;
    if (e < EE) atomicAdd(&deg[dst[e]], 1);
}

// ---- 3-phase coalesced scan ----
__global__ void k_scan_a(const int* __restrict__ deg, int* __restrict__ bsum) {
    __shared__ int ws[4];
    int b = blockIdx.x, tid = threadIdx.x;
    int i = b * 256 + tid;
    int v = (i < NN) ? deg[i] : 0;
    #pragma unroll
    for (int off = 1; off < 64; off <<= 1) v += __shfl_xor(v, off, 64);
    if ((tid & 63) == 0) ws[tid >> 6] = v;
    __syncthreads();
    if (tid == 0) bsum[b] = ws[0] + ws[1] + ws[2] + ws[3];
}

__global__ void k_scan_b(const int* __restrict__ bsum, int* __restrict__ boff) {
    __shared__ int wsum[4], wexc[4];
    int tid = threadIdx.x;
    int lane = tid & 63, wv = tid >> 6;
    int v = (tid < SCB) ? bsum[tid] : 0;
    int x = v;
    #pragma unroll
    for (int off = 1; off < 64; off <<= 1) {
        int y = __shfl_up(x, off, 64);
        if (lane >= off) x += y;
    }
    if (lane == 63) wsum[wv] = x;
    __syncthreads();
    if (tid == 0) { int run = 0; for (int w = 0; w < 4; w++) { wexc[w] = run; run += wsum[w]; } }
    __syncthreads();
    if (tid < SCB) boff[tid] = wexc[wv] + x - v;
}

__global__ void k_scan_c(const int* __restrict__ deg, const int* __restrict__ boff,
                         int* __restrict__ rp) {
    __shared__ int wsum[4], wexc[4];
    int b = blockIdx.x, tid = threadIdx.x;
    int i = b * 256 + tid;
    int v = (i < NN) ? deg[i] : 0;
    int lane = tid & 63, wv = tid >> 6;
    int x = v;
    #pragma unroll
    for (int off = 1; off < 64; off <<= 1) {
        int y = __shfl_up(x, off, 64);
        if (lane >= off) x += y;
    }
    if (lane == 63) wsum[wv] = x;
    __syncthreads();
    if (tid == 0) { int run = 0; for (int w = 0; w < 4; w++) { wexc[w] = run; run += wsum[w]; } }
    __syncthreads();
    if (i < NN) rp[i + 1] = boff[b] + wexc[wv] + x;
    if (b == 0 && tid == 0) rp[0] = 0;
}

__global__ void k_scatter(const int* src, const int* dst, const int* rp,
                          int* deg, int* cs) {
    int e = blockIdx.x * 256 + threadIdx.x;
    if (e < EE) {
        int d = dst[e];
        int pos = atomicSub(&deg[d], 1) - 1;
        cs[rp[d] + pos] = src[e];
    }
}

// Pack weights (fp16, transposed, padded):
// Bt1[l][128][128]  : pool, n<108,k<108 -> W_pool[l][k][n]
// BtA[l][108][256]  : app,  row n<108; k<108 -> W_app[l][k][n]; 128<=k<236 -> W_app[l][108+k-128][n]
__global__ void k_pack(const float* __restrict__ W_pool, const float* __restrict__ b_pool,
                       const float* __restrict__ W_app, const float* __restrict__ b_app,
                       const float* __restrict__ W_emb, const float* __restrict__ b_emb,
                       _Float16* Bt1, _Float16* BtA, float* bbP, float* bbA,
                       _Float16* BtE, float* bbE) {
    int r = blockIdx.x * 256 + threadIdx.x;
    if (r < NL * 128 * 128) {
        int l = r / (128 * 128); int t = r % (128 * 128); int n = t / 128, k = t % 128;
        float v = (n < HID && k < HID) ? W_pool[((size_t)l * HID + k) * HID + n] : 0.f;
        Bt1[r] = (_Float16)v; return;
    } r -= NL * 128 * 128;
    if (r < NL * 108 * 256) {
        int l = r / (108 * 256); int t = r % (108 * 256); int n = t / 256, k = t % 256;
        float v = 0.f;
        if (k < HID)                        v = W_app[((size_t)l * 216 + k) * HID + n];
        else if (k >= 128 && k < 128 + HID) v = W_app[((size_t)l * 216 + 108 + (k - 128)) * HID + n];
        BtA[r] = (_Float16)v; return;
    } r -= NL * 108 * 256;
    if (r < NL * 128) { int l = r / 128, n = r % 128; bbP[r] = (n < HID) ? b_pool[l * HID + n] : 0.f; return; } r -= NL * 128;
    if (r < NL * 128) { int l = r / 128, n = r % 128; bbA[r] = (n < HID) ? b_app[l * HID + n] : 0.f; return; } r -= NL * 128;
    if (r < 128 * 32) {
        int n = r / 32, k = r % 32;
        BtE[r] = (n < HID) ? (_Float16)W_emb[k * HID + n] : (_Float16)0.f; return;
    } r -= 128 * 32;
    if (r < 128) { bbE[r] = (r < HID) ? b_emb[r] : 0.f; }
}

// embed via MFMA: h16[M,128] = feat(fp32->fp16)[M,32] @ BtE^T + bias; h = fp32 copy
__global__ __launch_bounds__(256)
void k_embed_mm(const float* __restrict__ feat, const _Float16* __restrict__ BtE,
                const float* __restrict__ bias,
                float* __restrict__ h, _Float16* __restrict__ h16) {
    __shared__ _Float16 Bl[128 * 32];
    int tid = threadIdx.x;
    for (int i = tid; i < 128 * 32 / 8; i += 256)
        ((uint4*)Bl)[i] = ((const uint4*)BtE)[i];
    __syncthreads();
    int lane = tid & 63, wid = tid >> 6, lm = lane & 15, lq = lane >> 4;
    int m0 = blockIdx.x * 64;
    floatx4 acc[4][2];
    #pragma unroll
    for (int mi = 0; mi < 4; mi++)
        #pragma unroll
        for (int ni = 0; ni < 2; ni++) { floatx4 z = {0.f,0.f,0.f,0.f}; acc[mi][ni] = z; }
    f16x8 a[4], b[2];
    #pragma unroll
    for (int mi = 0; mi < 4; mi++) {
        int row = m0 + mi * 16 + lm;
        f16x8 av;
        if (row < NN) {
            const float4 v0 = *(const float4*)(feat + (size_t)row * 32 + lq * 8);
            const float4 v1 = *(const float4*)(feat + (size_t)row * 32 + lq * 8 + 4);
            av[0] = (_Float16)v0.x; av[1] = (_Float16)v0.y;
            av[2] = (_Float16)v0.z; av[3] = (_Float16)v0.w;
            av[4] = (_Float16)v1.x; av[5] = (_Float16)v1.y;
            av[6] = (_Float16)v1.z; av[7] = (_Float16)v1.w;
        } else {
            #pragma unroll
            for (int j = 0; j < 8; j++) av[j] = (_Float16)0.f;
        }
        a[mi] = av;
    }
    #pragma unroll
    for (int ni = 0; ni < 2; ni++) {
        int col = wid * 32 + ni * 16 + lm;
        b[ni] = *(const f16x8*)&Bl[col * 32 + lq * 8];
    }
    #pragma unroll
    for (int mi = 0; mi < 4; mi++)
        #pragma unroll
        for (int ni = 0; ni < 2; ni++)
            acc[mi][ni] = __builtin_amdgcn_mfma_f32_16x16x32_f16(a[mi], b[ni], acc[mi][ni], 0, 0, 0);
    #pragma unroll
    for (int mi = 0; mi < 4; mi++)
        #pragma unroll
        for (int ni = 0; ni < 2; ni++) {
            int col = wid * 32 + ni * 16 + lm;
            float bc = bias[col];
            #pragma unroll
            for (int r = 0; r < 4; r++) {
                int row = m0 + mi * 16 + lq * 4 + r;
                if (row < NN) {
                    float v = acc[mi][ni][r] + bc;
                    h16[(size_t)row * 128 + col] = (_Float16)v;
                    if (col < HID) h[(size_t)row * HID + col] = v;
                }
            }
        }
}

// mm1 (pool only): hp16 = fp16(relu(h16 @ Bt1^T + bias))
__global__ __launch_bounds__(256)
void k_mm1(const _Float16* __restrict__ A, const _Float16* __restrict__ Bt,
           const float* __restrict__ bias, _Float16* __restrict__ hp16) {
    __shared__ _Float16 Bl[128 * LDSK];
    int tid = threadIdx.x;
    for (int i = tid; i < 128 * 16; i += 256) {
        int rr = i >> 4, g = i & 15;
        *(uint4*)&Bl[rr * LDSK + g * 8] = *(const uint4*)(Bt + rr * 128 + g * 8);
    }
    __syncthreads();
    int lane = tid & 63, wid = tid >> 6, lm = lane & 15, lq = lane >> 4;
    int m0 = blockIdx.x * 64;
    floatx4 acc[4][2];
    #pragma unroll
    for (int mi = 0; mi < 4; mi++)
        #pragma unroll
        for (int ni = 0; ni < 2; ni++) { floatx4 z = {0.f,0.f,0.f,0.f}; acc[mi][ni] = z; }
    f16x8 zf = {(_Float16)0, (_Float16)0, (_Float16)0, (_Float16)0,
                (_Float16)0, (_Float16)0, (_Float16)0, (_Float16)0};
    #pragma unroll
    for (int ks = 0; ks < 4; ks++) {
        f16x8 a[4], b[2];
        #pragma unroll
        for (int mi = 0; mi < 4; mi++) {
            int row = m0 + mi * 16 + lm;
            a[mi] = (row < NN) ? *(const f16x8*)(A + (size_t)row * 128 + ks * 32 + lq * 8) : zf;
        }
        #pragma unroll
        for (int ni = 0; ni < 2; ni++)
            b[ni] = *(const f16x8*)&Bl[(wid * 32 + ni * 16 + lm) * LDSK + ks * 32 + lq * 8];
        #pragma unroll
        for (int mi = 0; mi < 4; mi++)
            #pragma unroll
            for (int ni = 0; ni < 2; ni++)
                acc[mi][ni] = __builtin_amdgcn_mfma_f32_16x16x32_f16(a[mi], b[ni], acc[mi][ni], 0, 0, 0);
    }
    #pragma unroll
    for (int mi = 0; mi < 4; mi++)
        #pragma unroll
        for (int ni = 0; ni < 2; ni++) {
            int col = wid * 32 + ni * 16 + lm;
            float bc = bias[col];
            #pragma unroll
            for (int r = 0; r < 4; r++) {
                int row = m0 + mi * 16 + lq * 4 + r;
                if (row < NN)
                    hp16[(size_t)row * 128 + col] = (_Float16)fmaxf(acc[mi][ni][r] + bc, 0.f);
            }
        }
}

// agg16[n][:] = fp16(mean over in-neighbors of hp16)
__global__ __launch_bounds__(128)
void k_agg(const _Float16* __restrict__ hp16, const int* __restrict__ rp,
           const int* __restrict__ cs, _Float16* __restrict__ agg16) {
    __shared__ float asl[8][128];
    int n = blockIdx.x, tid = threadIdx.x;
    int t = tid & 15, q = tid >> 4;
    int s0 = rp[n], s1 = rp[n + 1];
    float a[8];
    #pragma unroll
    for (int j = 0; j < 8; j++) a[j] = 0.f;
    int co = t * 8;
    for (int e = s0 + q; e < s1; e += 8) {
        f16x8 v = *(const f16x8*)(hp16 + (size_t)cs[e] * 128 + co);
        #pragma unroll
        for (int j = 0; j < 8; j++) a[j] += (float)v[j];
    }
    #pragma unroll
    for (int j = 0; j < 8; j++) asl[q][co + j] = a[j];
    __syncthreads();
    int col = tid;
    float s = 0.f;
    #pragma unroll
    for (int qq = 0; qq < 8; qq++) s += asl[qq][col];
    int dg = s1 - s0;
    float inv = 1.0f / (float)((dg > 1) ? dg : 1);
    agg16[(size_t)n * 128 + col] = (_Float16)(s * inv);
}

// app (fused K=256, no LDS for B — per-thread coalesced L1/L2-resident loads):
// bu = [h16|agg16] @ BtA^T + bias; l2norm -> relu -> h += ; write h fp32 + h16
__global__ __launch_bounds__(256)
void k_app_mm(const _Float16* __restrict__ Ah, const _Float16* __restrict__ Ag,
              const _Float16* __restrict__ Bt, const float* __restrict__ bias,
              float* __restrict__ h, _Float16* __restrict__ h16) {
    __shared__ float ssl[64 * 4];
    __shared__ float scl[64];
    int tid = threadIdx.x;
    int lane = tid & 63, wid = tid >> 6, lm = lane & 15, lq = lane >> 4;
    int m0 = blockIdx.x * 64;
    floatx4 acc[4][2];
    #pragma unroll
    for (int mi = 0; mi < 4; mi++)
        #pragma unroll
        for (int ni = 0; ni < 2; ni++) { floatx4 z = {0.f,0.f,0.f,0.f}; acc[mi][ni] = z; }
    f16x8 zf = {(_Float16)0, (_Float16)0, (_Float16)0, (_Float16)0,
                (_Float16)0, (_Float16)0, (_Float16)0, (_Float16)0};
    int colc[2], cval[2];
    #pragma unroll
    for (int ni = 0; ni < 2; ni++) {
        int col = wid * 32 + ni * 16 + lm;
        cval[ni] = (col < HID);
        colc[ni] = cval[ni] ? col : 0;   // clamp B row for masked cols
    }
    #pragma unroll
    for (int ks = 0; ks < 8; ks++) {
        const _Float16* Asrc = (ks < 4) ? Ah : Ag;
        int ko = (ks & 3) * 32 + lq * 8;
        f16x8 a[4], b[2];
        #pragma unroll
        for (int mi = 0; mi < 4; mi++) {
            int row = m0 + mi * 16 + lm;
            a[mi] = (row < NN) ? *(const f16x8*)(Asrc + (size_t)row * 128 + ko) : zf;
        }
        #pragma unroll
        for (int ni = 0; ni < 2; ni++)
            b[ni] = *(const f16x8*)(Bt + (size_t)colc[ni] * 256 + ks * 32 + lq * 8);
        #pragma unroll
        for (int mi = 0; mi < 4; mi++)
            #pragma unroll
            for (int ni = 0; ni < 2; ni++)
                acc[mi][ni] = __builtin_amdgcn_mfma_f32_16x16x32_f16(a[mi], b[ni], acc[mi][ni], 0, 0, 0);
    }
    // bias + masked sum of squares
    #pragma unroll
    for (int ni = 0; ni < 2; ni++) {
        int col = wid * 32 + ni * 16 + lm;
        float bc = bias[col];
        #pragma unroll
        for (int mi = 0; mi < 4; mi++)
            #pragma unroll
            for (int r = 0; r < 4; r++) acc[mi][ni][r] += bc;
    }
    float ss[4][4];
    #pragma unroll
    for (int mi = 0; mi < 4; mi++)
        #pragma unroll
        for (int r = 0; r < 4; r++) {
            float c0 = cval[0] ? acc[mi][0][r] : 0.f;
            float c1 = cval[1] ? acc[mi][1][r] : 0.f;
            ss[mi][r] = c0 * c0 + c1 * c1;
        }
    #pragma unroll
    for (int off = 1; off < 16; off <<= 1)
        #pragma unroll
        for (int mi = 0; mi < 4; mi++)
            #pragma unroll
            for (int r = 0; r < 4; r++)
                ss[mi][r] += __shfl_xor(ss[mi][r], off, 64);
    if (lm == 0) {
        #pragma unroll
        for (int mi = 0; mi < 4; mi++)
            #pragma unroll
            for (int r = 0; r < 4; r++)
                ssl[(mi * 16 + lq * 4 + r) * 4 + wid] = ss[mi][r];
    }
    __syncthreads();
    if (tid < 64) {
        float s = ssl[tid * 4] + ssl[tid * 4 + 1] + ssl[tid * 4 + 2] + ssl[tid * 4 + 3];
        scl[tid] = 1.0f / fmaxf(sqrtf(s), 1e-12f);
    }
    __syncthreads();
    #pragma unroll
    for (int mi = 0; mi < 4; mi++)
        #pragma unroll
        for (int ni = 0; ni < 2; ni++) {
            int col = wid * 32 + ni * 16 + lm;
            if (col < HID) {
                #pragma unroll
                for (int r = 0; r < 4; r++) {
                    int rl = mi * 16 + lq * 4 + r;
                    int row = m0 + rl;
                    if (row < NN) {
                        float v = fmaxf(acc[mi][ni][r] * scl[rl], 0.f);
                        float hn = h[(size_t)row * HID + col] + v;
                        h[(size_t)row * HID + col] = hn;
                        h16[(size_t)row * 128 + col] = (_Float16)hn;
                    }
                }
            }
        }
}

// readout phase 1: per-(graph, slice) partial column sums of h
__global__ __launch_bounds__(128)
void k_seg(const float* __restrict__ h, const int* __restrict__ gid,
           float* __restrict__ hgp) {
    __shared__ int se[2];
    int g = blockIdx.x, sl = blockIdx.y, tid = threadIdx.x;
    if (tid < 2) {
        int key = g + tid, lo = 0, hi = NN;
        while (lo < hi) {
            int mid = (lo + hi) >> 1;
            if (gid[mid] < key) lo = mid + 1; else hi = mid;
        }
        se[tid] = lo;
    }
    __syncthreads();
    int s = se[0], e = se[1];
    int cnt = e - s;
    int chunk = (cnt + RS - 1) / RS;
    int ls = s + sl * chunk;
    int le = min(e, ls + chunk);
    if (tid < HID) {
        float acc = 0.f;
        for (int n = ls; n < le; n++) acc += h[(size_t)n * HID + tid];
        hgp[((size_t)g * RS + sl) * HID + tid] = acc;
    }
}

// readout phase 2: combine partials, mean, 3-layer MLP
__global__ __launch_bounds__(128)
void k_mlp(const float* __restrict__ hgp, const int* __restrict__ gid,
           const float* __restrict__ W1, const float* __restrict__ b1,
           const float* __restrict__ W2, const float* __restrict__ b2,
           const float* __restrict__ W3, const float* __restrict__ b3,
           float* __restrict__ out) {
    __shared__ float hg[HID];
    __shared__ float y1[54];
    __shared__ float y2[27];
    __shared__ int se[2];
    int g = blockIdx.x, tid = threadIdx.x;
    if (tid < 2) {
        int key = g + tid, lo = 0, hi = NN;
        while (lo < hi) {
            int mid = (lo + hi) >> 1;
            if (gid[mid] < key) lo = mid + 1; else hi = mid;
        }
        se[tid] = lo;
    }
    __syncthreads();
    int cnt = se[1] - se[0];
    if (tid < HID) {
        float acc = 0.f;
        #pragma unroll
        for (int sl = 0; sl < RS; sl++) acc += hgp[((size_t)g * RS + sl) * HID + tid];
        hg[tid] = acc / (float)((cnt > 1) ? cnt : 1);
    }
    __syncthreads();
    if (tid < 54) {
        float a = b1[tid];
        for (int k = 0; k < HID; k++) a += hg[k] * W1[k * 54 + tid];
        y1[tid] = fmaxf(a, 0.f);
    }
    __syncthreads();
    if (tid < 27) {
        float a = b2[tid];
        for (int k = 0; k < 54; k++) a += y1[k] * W2[k * 27 + tid];
        y2[tid] = fmaxf(a, 0.f);
    }
    __syncthreads();
    if (tid < 10) {
        float a = b3[tid];
        for (int k = 0; k < 27; k++) a += y2[k] * W3[k * 10 + tid];
        out[g * 10 + tid] = a;
    }
}

extern "C" void kernel_launch(void* const* d_in, const int* in_sizes, int n_in,
                              void* d_out, int out_size, void* d_ws, size_t ws_size,
                              hipStream_t stream) {
    float* out = (float*)d_out;
    (void)in_sizes; (void)n_in; (void)ws_size; (void)out_size;

    const float* feat   = (const float*)d_in[0];
    const int*   src    = (const int*)d_in[4];
    const int*   dst    = (const int*)d_in[5];
    const int*   gid    = (const int*)d_in[6];
    const float* W_emb  = (const float*)d_in[7];
    const float* b_emb  = (const float*)d_in[8];
    const float* W_pool = (const float*)d_in[9];
    const float* b_pool = (const float*)d_in[10];
    const float* W_app  = (const float*)d_in[11];
    const float* b_app  = (const float*)d_in[12];
    const float* W1     = (const float*)d_in[13];
    const float* b1     = (const float*)d_in[14];
    const float* W2     = (const float*)d_in[15];
    const float* b2     = (const float*)d_in[16];
    const float* W3     = (const float*)d_in[17];
    const float* b3     = (const float*)d_in[18];

    char* ws = (char*)d_ws;
    size_t off = 0;
    auto take = [&](size_t bytes) { char* p = ws + off; off += (bytes + 255) & ~(size_t)255; return p; };
    float*     h     = (float*)take((size_t)NN * HID * 4);
    _Float16*  h16   = (_Float16*)take((size_t)NN * 128 * 2);
    _Float16*  hp16  = (_Float16*)take((size_t)NN * 128 * 2);
    _Float16*  agg16 = (_Float16*)take((size_t)NN * 128 * 2);
    int*       cs    = (int*)take((size_t)EE * 4);
    int*       deg   = (int*)take((size_t)NN * 4);
    int*       rp    = (int*)take((size_t)(NN + 1) * 4);
    int*       bsum  = (int*)take((size_t)SCB * 4);
    int*       boff  = (int*)take((size_t)SCB * 4);
    float*     hgp   = (float*)take((size_t)GG * RS * HID * 4);
    _Float16*  Bt1   = (_Float16*)take((size_t)NL * 128 * 128 * 2);
    _Float16*  BtA   = (_Float16*)take((size_t)NL * 108 * 256 * 2);
    float*     bbP   = (float*)take((size_t)NL * 128 * 4);
    float*     bbA   = (float*)take((size_t)NL * 128 * 4);
    _Float16*  BtE   = (_Float16*)take((size_t)128 * 32 * 2);
    float*     bbE   = (float*)take((size_t)128 * 4);

    hipLaunchKernelGGL(k_zero, dim3((NN + 255) / 256), dim3(256), 0, stream, deg);
    hipLaunchKernelGGL(k_hist, dim3((EE + 255) / 256), dim3(256), 0, stream, dst, deg);
    hipLaunchKernelGGL(k_scan_a, dim3(SCB), dim3(256), 0, stream, deg, bsum);
    hipLaunchKernelGGL(k_scan_b, dim3(1), dim3(256), 0, stream, bsum, boff);
    hipLaunchKernelGGL(k_scan_c, dim3(SCB), dim3(256), 0, stream, deg, boff, rp);
    hipLaunchKernelGGL(k_scatter, dim3((EE + 255) / 256), dim3(256), 0, stream,
                       src, dst, rp, deg, cs);

    const int PACK_TOTAL = NL * 128 * 128 + NL * 108 * 256 + NL * 128 + NL * 128 + 128 * 32 + 128;
    hipLaunchKernelGGL(k_pack, dim3((PACK_TOTAL + 255) / 256), dim3(256), 0, stream,
                       W_pool, b_pool, W_app, b_app, W_emb, b_emb,
                       Bt1, BtA, bbP, bbA, BtE, bbE);

    hipLaunchKernelGGL(k_embed_mm, dim3(MB), dim3(256), 0, stream,
                       feat, BtE, bbE, h, h16);

    for (int l = 0; l < NL; l++) {
        hipLaunchKernelGGL(k_mm1, dim3(MB), dim3(256), 0, stream,
                           h16, Bt1 + (size_t)l * 128 * 128, bbP + (size_t)l * 128, hp16);
        hipLaunchKernelGGL(k_agg, dim3(NN), dim3(128), 0, stream, hp16, rp, cs, agg16);
        hipLaunchKernelGGL(k_app_mm, dim3(MB), dim3(256), 0, stream,
                           h16, agg16, BtA + (size_t)l * 108 * 256, bbA + (size_t)l * 128,
                           h, h16);
    }
    hipLaunchKernelGGL(k_seg, dim3(GG, RS), dim3(128), 0, stream, h, gid, hgp);
    hipLaunchKernelGGL(k_mlp, dim3(GG), dim3(128), 0, stream,
                       hgp, gid, W1, b1, W2, b2, W3, b3, out);
}